// Round 11
// baseline (1907.147 us; speedup 1.0000x reference)
//
#include <hip/hip_runtime.h>
#include <math.h>

#define T_TOK 8192
#define DM 1024
#define DFF 4096
#define NE 8
#define NPAIR 16384
#define MAXTILE 72
#define LN_EPS 1e-5f

typedef __attribute__((ext_vector_type(8))) short bf16x8;
typedef __attribute__((ext_vector_type(4))) float f32x4;
typedef __attribute__((ext_vector_type(4))) unsigned short u16x4;
typedef __attribute__((ext_vector_type(8))) unsigned short u16x8;
typedef unsigned int u32;
typedef unsigned short u16;

__device__ __forceinline__ u16 f2bf(float f) {
  union { float f; u32 u; } v; v.f = f;
  u32 r = (v.u + 0x7fffu + ((v.u >> 16) & 1u)) >> 16;
  return (u16)r;
}
__device__ __forceinline__ float bf2f(u16 h) {
  union { u32 u; float f; } v; v.u = ((u32)h) << 16; return v.f;
}

__device__ __forceinline__ void gll16(const void* g, void* l) {
  __builtin_amdgcn_global_load_lds(
      (const __attribute__((address_space(1))) u32*)g,
      (__attribute__((address_space(3))) u32*)l, 16, 0, 0);
}

// ---------------- embed ----------------
__global__ __launch_bounds__(256) void embed_kernel(const int* __restrict__ tok,
    const float* __restrict__ sym, const float* __restrict__ emb,
    float* __restrict__ x, u16* __restrict__ xh, u16* __restrict__ xl)
{
  int t = blockIdx.x;
  int b = t >> 11;
  int tk = tok[t];
  int d = threadIdx.x * 4;
  f32x4 e = *(const f32x4*)(emb + (size_t)tk * DM + d);
  f32x4 s = *(const f32x4*)(sym + (size_t)b * DM + d);
  f32x4 v = e + s;
  *(f32x4*)(x + (size_t)t * DM + d) = v;
  u16x4 hv, lv;
#pragma unroll
  for (int j = 0; j < 4; ++j) {
    u16 hb = f2bf(v[j]);
    hv[j] = hb;
    lv[j] = f2bf(v[j] - bf2f(hb));
  }
  *(u16x4*)(xh + (size_t)t * DM + d) = hv;
  *(u16x4*)(xl + (size_t)t * DM + d) = lv;
}

// ---------------- layer-0 gating: f64, top-2 only ----------------
__global__ __launch_bounds__(256) void gate_kernel(const float* __restrict__ x,
    const float* __restrict__ gw, const float* __restrict__ gb,
    int* __restrict__ topk_idx, float* __restrict__ topk_w)
{
  int lane = threadIdx.x & 63;
  int t = blockIdx.x * 4 + (threadIdx.x >> 6);
  const float* xr = x + (size_t)t * DM;
  double a[8] = {0,0,0,0,0,0,0,0};
  for (int i = 0; i < 16; ++i) {
    int d = i * 64 + lane;
    double xv = (double)xr[d];
    const float* g = gw + (size_t)d * NE;
#pragma unroll
    for (int j = 0; j < 8; ++j) a[j] += xv * (double)g[j];
  }
#pragma unroll
  for (int j = 0; j < 8; ++j) {
#pragma unroll
    for (int sh = 32; sh; sh >>= 1) a[j] += __shfl_xor(a[j], sh);
  }
  if (lane == 0) {
#pragma unroll
    for (int j = 0; j < 8; ++j) a[j] += (double)gb[j];
    double m = a[0];
    for (int j = 1; j < 8; ++j) m = a[j] > m ? a[j] : m;
    double p[8], sum = 0.0;
    for (int j = 0; j < 8; ++j) { p[j] = exp(a[j] - m); sum += p[j]; }
    for (int j = 0; j < 8; ++j) p[j] /= sum;
    int j0 = 0; double b0 = p[0];
    for (int j = 1; j < 8; ++j) if (p[j] > b0) { b0 = p[j]; j0 = j; }
    int j1 = (j0 == 0) ? 1 : 0; double b1v = p[j1];
    for (int j = 0; j < 8; ++j) if (j != j0 && p[j] > b1v) { b1v = p[j]; j1 = j; }
    topk_idx[t*2]   = j0; topk_idx[t*2+1] = j1;
    topk_w[t*2]     = (float)b0; topk_w[t*2+1] = (float)b1v;
  }
}

// meta: [0..7]=totals, [8..16]=offsets, [31]=ntiles, [32..32+MAXTILE)=tiletab,
//       [168..423]=blockcnt[32][8], [424..679]=blockbase[32][8]
__global__ __launch_bounds__(256) void count_kernel(const int* __restrict__ topk_idx,
    int* __restrict__ meta)
{
  __shared__ int hist[8];
  int tid = threadIdx.x;
  if (tid < 8) hist[tid] = 0;
  __syncthreads();
  int t = blockIdx.x * 256 + tid;
  atomicAdd(&hist[topk_idx[t*2] & 7], 1);
  atomicAdd(&hist[topk_idx[t*2+1] & 7], 1);
  __syncthreads();
  if (tid < 8) meta[168 + blockIdx.x * 8 + tid] = hist[tid];
}

__global__ __launch_bounds__(64) void scan_kernel(int* __restrict__ meta)
{
  __shared__ int tot[8], off[9], tb[8];
  int lane = threadIdx.x;
  if (lane < 8) {
    int s = 0;
    for (int b = 0; b < 32; ++b) s += meta[168 + b * 8 + lane];
    tot[lane] = s;
  }
  __syncthreads();
  if (lane == 0) {
    int s = 0, nt = 0;
    for (int e = 0; e < 8; ++e) {
      off[e] = s; s += tot[e];
      tb[e] = nt; nt += (tot[e] + 255) >> 8;
    }
    off[8] = s;
    meta[31] = nt;
    for (int i = nt; i < MAXTILE; ++i) meta[32 + i] = -1;
  }
  __syncthreads();
  if (lane < 9) meta[8 + lane] = off[lane];
  if (lane < 8) {
    meta[lane] = tot[lane];
    int n = (tot[lane] + 255) >> 8;
    for (int i = 0; i < n; ++i) meta[32 + tb[lane] + i] = (lane << 16) | i;
    int run = off[lane];
    for (int b = 0; b < 32; ++b) {
      meta[424 + b * 8 + lane] = run;
      run += meta[168 + b * 8 + lane];
    }
  }
}

__global__ __launch_bounds__(256) void scatter_kernel(int* __restrict__ topk_idx,
    const int* __restrict__ meta, int* __restrict__ pair_token)
{
  __shared__ int hist[8];
  __shared__ int base[8];
  int tid = threadIdx.x;
  if (tid < 8) { hist[tid] = 0; base[tid] = meta[424 + blockIdx.x * 8 + tid]; }
  __syncthreads();
  int t = blockIdx.x * 256 + tid;
#pragma unroll
  for (int k = 0; k < 2; ++k) {
    int e = topk_idx[t*2 + k] & 7;
    int pos = atomicAdd(&hist[e], 1);
    int slot = base[e] + pos;
    pair_token[slot] = t;
    topk_idx[t*2 + k] = e | (slot << 3);
  }
}

// ------------- weight transpose+split: f32 [K][N] -> bf16 hi/lo [N][K] -------------
template<bool LO>
__global__ __launch_bounds__(256) void transpose_kernel(const float* __restrict__ src,
    u16* __restrict__ dsth, u16* __restrict__ dstl, int K, int N)
{
  __shared__ float tile[64][65];
  int e = blockIdx.z;
  const float* s = src + (size_t)e * K * N;
  size_t dbase = (size_t)e * K * N;
  int n0 = blockIdx.x * 64, k0 = blockIdx.y * 64;
  int tid = threadIdx.x;
  int nl = tid & 63;
  int kq = tid >> 6;
#pragma unroll
  for (int j = 0; j < 16; ++j) {
    int kl = j * 4 + kq;
    tile[nl][kl] = s[(size_t)(k0 + kl) * N + n0 + nl];
  }
  __syncthreads();
#pragma unroll
  for (int it = 0; it < 2; ++it) {
    int task = it * 256 + tid;
    int nr = task >> 3;
    int ch = task & 7;
    u16x8 oh, ol;
#pragma unroll
    for (int j = 0; j < 8; ++j) {
      float v = tile[nr][ch*8 + j];
      u16 hb = f2bf(v);
      oh[j] = hb;
      if (LO) ol[j] = f2bf(v - bf2f(hb));
    }
    size_t doff = dbase + (size_t)(n0 + nr) * K + k0 + ch*8;
    *(u16x8*)(dsth + doff) = oh;
    if (LO) *(u16x8*)(dstl + doff) = ol;
  }
}

// ---- W2G[e] = w2[e] @ gw1 ----
__global__ __launch_bounds__(256) void w2g_kernel(const float* __restrict__ w2,
    const float* __restrict__ gw, float* __restrict__ w2g)
{
  int wid = blockIdx.x * 4 + (threadIdx.x >> 6);
  int lane = threadIdx.x & 63;
  int e = wid >> 12, f = wid & 4095;
  const float* row = w2 + ((size_t)e * DFF + f) * DM;
  float a0=0,a1=0,a2=0,a3=0,a4=0,a5=0,a6=0,a7=0;
  for (int i = 0; i < 4; ++i) {
    int d0 = i * 256 + lane * 4;
    f32x4 xv = *(const f32x4*)(row + d0);
#pragma unroll
    for (int q = 0; q < 4; ++q) {
      const f32x4* gr = (const f32x4*)(gw + (size_t)(d0 + q) * 8);
      f32x4 g0 = gr[0], g1 = gr[1];
      float xq = xv[q];
      a0 += xq*g0.x; a1 += xq*g0.y; a2 += xq*g0.z; a3 += xq*g0.w;
      a4 += xq*g1.x; a5 += xq*g1.y; a6 += xq*g1.z; a7 += xq*g1.w;
    }
  }
  float acc[8] = {a0,a1,a2,a3,a4,a5,a6,a7};
#pragma unroll
  for (int j = 0; j < 8; ++j) {
#pragma unroll
    for (int sh = 32; sh; sh >>= 1) acc[j] += __shfl_xor(acc[j], sh);
  }
  if (lane == 0) {
#pragma unroll
    for (int j = 0; j < 8; ++j) w2g[(size_t)wid * 8 + j] = acc[j];
  }
}

__global__ __launch_bounds__(256) void b2g_kernel(const float* __restrict__ b2,
    const float* __restrict__ gw, float* __restrict__ b2g)
{
  int w = blockIdx.x * 4 + (threadIdx.x >> 6);
  int lane = threadIdx.x & 63;
  int e = w >> 3, j = w & 7;
  float acc = 0.f;
  for (int i = 0; i < 16; ++i) {
    int d = i * 64 + lane;
    acc += b2[(size_t)e * DM + d] * gw[(size_t)d * 8 + j];
  }
#pragma unroll
  for (int sh = 32; sh; sh >>= 1) acc += __shfl_xor(acc, sh);
  if (lane == 0) b2g[w] = acc;
}

// ---- pair logits ----
__global__ __launch_bounds__(256) void pairlogit_kernel(const u16* __restrict__ hh,
    const u16* __restrict__ hl, const int* __restrict__ off,
    const float* __restrict__ w2g, float* __restrict__ R)
{
  int p = blockIdx.x * 4 + (threadIdx.x >> 6);
  int lane = threadIdx.x & 63;
  int e = 0;
#pragma unroll
  for (int j = 1; j < 8; ++j) e += (p >= off[j]) ? 1 : 0;
  const float* wg = w2g + (size_t)e * DFF * 8;
  const u16* ph = hh + (size_t)p * DFF;
  const u16* pl = hl + (size_t)p * DFF;
  float a0=0,a1=0,a2=0,a3=0,a4=0,a5=0,a6=0,a7=0;
  for (int i = 0; i < 8; ++i) {
    int f0 = i * 512 + lane * 8;
    u16x8 vh = *(const u16x8*)(ph + f0);
    u16x8 vl = *(const u16x8*)(pl + f0);
#pragma unroll
    for (int q = 0; q < 8; ++q) {
      float hv = bf2f(vh[q]) + bf2f(vl[q]);
      const f32x4* wr = (const f32x4*)(wg + (size_t)(f0 + q) * 8);
      f32x4 g0 = wr[0], g1 = wr[1];
      a0 += hv*g0.x; a1 += hv*g0.y; a2 += hv*g0.z; a3 += hv*g0.w;
      a4 += hv*g1.x; a5 += hv*g1.y; a6 += hv*g1.z; a7 += hv*g1.w;
    }
  }
  float acc[8] = {a0,a1,a2,a3,a4,a5,a6,a7};
#pragma unroll
  for (int j = 0; j < 8; ++j) {
#pragma unroll
    for (int sh = 32; sh; sh >>= 1) acc[j] += __shfl_xor(acc[j], sh);
  }
  if (lane == 0) {
#pragma unroll
    for (int j = 0; j < 8; ++j) R[(size_t)p * 8 + j] = acc[j];
  }
}

// ---- layer-1 gate ----
__global__ __launch_bounds__(256) void gate1_kernel(const float* __restrict__ R,
    const float* __restrict__ b2g, const float* __restrict__ gb,
    int* __restrict__ topk_idx, float* __restrict__ topk_w)
{
  int t = blockIdx.x * 256 + threadIdx.x;
  int v0 = topk_idx[t*2], v1 = topk_idx[t*2+1];
  int e0 = v0 & 7, e1 = v1 & 7;
  int s0 = v0 >> 3, s1 = v1 >> 3;
  double w0 = (double)topk_w[t*2], w1 = (double)topk_w[t*2+1];
  double a[8];
#pragma unroll
  for (int j = 0; j < 8; ++j)
    a[j] = w0 * ((double)R[(size_t)s0*8+j] + (double)b2g[e0*8+j])
         + w1 * ((double)R[(size_t)s1*8+j] + (double)b2g[e1*8+j])
         + (double)gb[j];
  double m = a[0];
  for (int j = 1; j < 8; ++j) m = a[j] > m ? a[j] : m;
  double p[8], sum = 0.0;
  for (int j = 0; j < 8; ++j) { p[j] = exp(a[j] - m); sum += p[j]; }
  for (int j = 0; j < 8; ++j) p[j] /= sum;
  int j0 = 0; double b0 = p[0];
  for (int j = 1; j < 8; ++j) if (p[j] > b0) { b0 = p[j]; j0 = j; }
  int j1 = (j0 == 0) ? 1 : 0; double b1v = p[j1];
  for (int j = 0; j < 8; ++j) if (j != j0 && p[j] > b1v) { b1v = p[j]; j1 = j; }
  topk_idx[t*2]   = j0; topk_idx[t*2+1] = j1;
  topk_w[t*2]     = (float)b0; topk_w[t*2+1] = (float)b1v;
}

// ====== 256x256 grouped GEMM, BK=64, 8-phase schedule, counted vmcnt ======
// LDS: A,B each [parity][khalf][256 rows][32 k] = 4x16KB -> 128 KiB total.
// Per tile t (4 phases): ph1{rdB(k0)+rdA(k0,m0-3); stage A-kh1(t+1); bar; MFMA; bar}
//   ph2{rdA(k0,m4-7); stage B-kh1(t+1); bar; MFMA; GATE kh1(t); bar; fence}
//   ph3{rdB(k1)+rdA(k1,m0-3); stage A-kh0(t+2); bar; MFMA; bar}
//   ph4{rdA(k1,m4-7); stage B-kh0(t+2); bar; MFMA; GATE kh0(t+1); bar; fence}
// Ledger (2 gll16 per half-stage): steady outstanding at each gate = 12 loads;
// gate retires the needed oldest pair -> vmcnt(8); tail: 8 -> 4 -> 0 (derived).
// MODE 0: outh=bf16(gelu); MODE 1: split-bf16; MODE 2: y[slot]=acc+bias.
template<int K0, int NSEG, int NTOT, bool GATHER, int MODE>
__global__ __launch_bounds__(512, 2) void gemm256_kernel(
    const u16* __restrict__ Ah, const u16* __restrict__ Al,
    const u16* __restrict__ Bh, const u16* __restrict__ Bl,
    const float* __restrict__ bias, const int* __restrict__ off,
    const int* __restrict__ tiletab, const int* __restrict__ pair_token,
    u16* __restrict__ outh, u16* __restrict__ outl, float* __restrict__ outy)
{
  constexpr int NT = (K0 * NSEG) / 64;
  static_assert(NT >= 2, "");
  const int tt = tiletab[blockIdx.y];
  if (tt < 0) return;
  const int e  = tt >> 16;
  const int mt = tt & 0xffff;
  const int off_e = off[e], off_e1 = off[e + 1];
  const int p0 = off_e + mt * 256;
  const int NX = gridDim.x;
  int bx = blockIdx.x;
  int ntile = ((NX & 7) == 0) ? ((bx & 7) * (NX >> 3) + (bx >> 3)) : bx;
  const int n0 = ntile * 256;

  __shared__ __align__(16) u16 ALs[2][2][8192];
  __shared__ __align__(16) u16 BLs[2][2][8192];

  const int tid  = threadIdx.x;
  const int lane = tid & 63;
  const int wave = tid >> 6;
  const int wm = wave >> 2;      // 0..1
  const int wn = wave & 3;       // 0..3
  const int wbase = tid & 448;   // wave*64

  // per-thread staging offsets (pre-swizzled source, rule-21 pair with read swz)
  size_t aoff[2], boff[2];
#pragma unroll
  for (int i = 0; i < 2; ++i) {
    int c = i * 512 + tid;
    int r = c >> 2;
    int cs = (c & 3) ^ ((r >> 1) & 3);
    int idx = p0 + r;
    if (idx >= off_e1) idx = p0;
    int ar = GATHER ? pair_token[idx] : idx;
    aoff[i] = (size_t)ar * K0 + (size_t)(cs * 8);
    boff[i] = ((size_t)e * NTOT + n0 + r) * K0 + (size_t)(cs * 8);
  }

  auto stageA = [&](int t, int kh) {
    int kk = t * 64 + kh * 32;
    int seg = (NSEG == 3) ? (kk >> 10) : 0;
    int kc  = (NSEG == 3) ? (kk & (K0 - 1)) : kk;
    const u16* base = (NSEG == 3 && seg == 1) ? Al : Ah;
    u16* dst = &ALs[t & 1][kh][0];
#pragma unroll
    for (int i = 0; i < 2; ++i)
      gll16(base + aoff[i] + kc, dst + (i * 512 + wbase) * 8);
  };
  auto stageB = [&](int t, int kh) {
    int kk = t * 64 + kh * 32;
    int seg = (NSEG == 3) ? (kk >> 10) : 0;
    int kc  = (NSEG == 3) ? (kk & (K0 - 1)) : kk;
    const u16* base = (NSEG == 3 && seg == 2) ? Bl : Bh;
    u16* dst = &BLs[t & 1][kh][0];
#pragma unroll
    for (int i = 0; i < 2; ++i)
      gll16(base + boff[i] + kc, dst + (i * 512 + wbase) * 8);
  };

  f32x4 acc[8][4];
  const f32x4 fzero = {0.f, 0.f, 0.f, 0.f};
#pragma unroll
  for (int m = 0; m < 8; ++m)
#pragma unroll
    for (int n = 0; n < 4; ++n) acc[m][n] = fzero;

  auto rdA4 = [&](bf16x8* dst, int par, int kh, int mbase) {
    const u16* L = &ALs[par][kh][0];
#pragma unroll
    for (int mf = 0; mf < 4; ++mf) {
      int row = wm * 128 + (mbase + mf) * 16 + (lane & 15);
      dst[mf] = *(const bf16x8*)&L[row * 32 + (((lane >> 4) ^ ((row >> 1) & 3)) << 3)];
    }
  };
  auto rdB4 = [&](bf16x8* dst, int par, int kh) {
    const u16* L = &BLs[par][kh][0];
#pragma unroll
    for (int nf = 0; nf < 4; ++nf) {
      int row = wn * 64 + nf * 16 + (lane & 15);
      dst[nf] = *(const bf16x8*)&L[row * 32 + (((lane >> 4) ^ ((row >> 1) & 3)) << 3)];
    }
  };

#define MMBLK(MB, A4, B4)                                                        \
  {                                                                              \
    __builtin_amdgcn_s_setprio(1);                                               \
    _Pragma("unroll")                                                            \
    for (int mf = 0; mf < 4; ++mf)                                               \
      _Pragma("unroll")                                                          \
      for (int nf = 0; nf < 4; ++nf)                                             \
        acc[(MB) + mf][nf] = __builtin_amdgcn_mfma_f32_16x16x32_bf16(            \
            (A4)[mf], (B4)[nf], acc[(MB) + mf][nf], 0, 0, 0);                    \
    __builtin_amdgcn_s_setprio(0);                                               \
  }

  // ---- prologue: stage kh0(0), kh1(0), kh0(1); gate kh0(0) ----
  stageA(0, 0); stageB(0, 0);
  stageA(0, 1); stageB(0, 1);
  stageA(1, 0); stageB(1, 0);
  asm volatile("s_waitcnt vmcnt(8)" ::: "memory");
  __builtin_amdgcn_s_barrier();
  asm volatile("" ::: "memory");

  for (int t = 0; t < NT; ++t) {
    const int par = t & 1;
    bf16x8 bA[4], aA[4], aB[4], bC[4], aC[4], aD[4];
    // ---- ph1 ----
    rdB4(bA, par, 0);
    rdA4(aA, par, 0, 0);
    if (t + 1 < NT) stageA(t + 1, 1);
    __builtin_amdgcn_s_barrier();
    MMBLK(0, aA, bA);
    __builtin_amdgcn_s_barrier();
    // ---- ph2 ----
    rdA4(aB, par, 0, 4);
    if (t + 1 < NT) stageB(t + 1, 1);
    __builtin_amdgcn_s_barrier();
    MMBLK(4, aB, bA);
    if (t + 1 < NT) { asm volatile("s_waitcnt vmcnt(8)" ::: "memory"); }
    else            { asm volatile("s_waitcnt vmcnt(0)" ::: "memory"); }
    __builtin_amdgcn_s_barrier();
    asm volatile("" ::: "memory");
    // ---- ph3 ----
    rdB4(bC, par, 1);
    rdA4(aC, par, 1, 0);
    if (t + 2 < NT) stageA(t + 2, 0);
    __builtin_amdgcn_s_barrier();
    MMBLK(0, aC, bC);
    __builtin_amdgcn_s_barrier();
    // ---- ph4 ----
    rdA4(aD, par, 1, 4);
    if (t + 2 < NT) stageB(t + 2, 0);
    __builtin_amdgcn_s_barrier();
    MMBLK(4, aD, bC);
    if (t + 1 < NT) {
      if (t + 2 < NT) { asm volatile("s_waitcnt vmcnt(8)" ::: "memory"); }
      else            { asm volatile("s_waitcnt vmcnt(4)" ::: "memory"); }
      __builtin_amdgcn_s_barrier();
      asm volatile("" ::: "memory");
    }
  }
#undef MMBLK

  // ---- epilogue ----
  float bv[4];
#pragma unroll
  for (int nf = 0; nf < 4; ++nf)
    bv[nf] = bias[(size_t)e * NTOT + n0 + wn * 64 + nf * 16 + (lane & 15)];

#pragma unroll
  for (int mf = 0; mf < 8; ++mf) {
    int rbase = p0 + wm * 128 + mf * 16 + ((lane >> 4) << 2);
#pragma unroll
    for (int nf = 0; nf < 4; ++nf) {
      int col = n0 + wn * 64 + nf * 16 + (lane & 15);
#pragma unroll
      for (int r = 0; r < 4; ++r) {
        int rowp = rbase + r;
        if (rowp < off_e1) {
          float v = acc[mf][nf][r] + bv[nf];
          if constexpr (MODE <= 1) {
            v = 0.5f * v * (1.0f + erff(v * 0.70710678118654752f));
            u16 hb = f2bf(v);
            outh[(size_t)rowp * NTOT + col] = hb;
            if constexpr (MODE == 1)
              outl[(size_t)rowp * NTOT + col] = f2bf(v - bf2f(hb));
          } else {
            outy[(size_t)rowp * NTOT + col] = v;
          }
        }
      }
    }
  }
}

// ---------------- combine (layer 0) ----------------
__global__ __launch_bounds__(256) void combine0_kernel(const float* __restrict__ y,
    const int* __restrict__ topk_idx, const float* __restrict__ topk_w,
    u16* __restrict__ xh)
{
  int t = blockIdx.x;
  int d = threadIdx.x * 4;
  int s0 = topk_idx[t*2] >> 3, s1 = topk_idx[t*2 + 1] >> 3;
  float w0 = topk_w[t*2], w1 = topk_w[t*2 + 1];
  f32x4 y0 = *(const f32x4*)(y + (size_t)s0 * DM + d);
  f32x4 y1 = *(const f32x4*)(y + (size_t)s1 * DM + d);
  f32x4 v = y0 * w0 + y1 * w1;
  u16x4 hv;
#pragma unroll
  for (int j = 0; j < 4; ++j) hv[j] = f2bf(v[j]);
  *(u16x4*)(xh + (size_t)t * DM + d) = hv;
}

// ---------------- combine (layer 1) + LayerNorm ----------------
__global__ __launch_bounds__(256) void combine1_ln_kernel(const float* __restrict__ y,
    const int* __restrict__ topk_idx, const float* __restrict__ topk_w,
    const float* __restrict__ g, const float* __restrict__ b, float* __restrict__ out)
{
  int t = blockIdx.x;
  int d = threadIdx.x * 4;
  int s0 = topk_idx[t*2] >> 3, s1 = topk_idx[t*2 + 1] >> 3;
  float w0 = topk_w[t*2], w1 = topk_w[t*2 + 1];
  f32x4 y0 = *(const f32x4*)(y + (size_t)s0 * DM + d);
  f32x4 y1 = *(const f32x4*)(y + (size_t)s1 * DM + d);
  f32x4 v = y0 * w0 + y1 * w1;
  float s = v.x + v.y + v.z + v.w;
  float sq = v.x*v.x + v.y*v.y + v.z*v.z + v.w*v.w;
#pragma unroll
  for (int sh = 32; sh; sh >>= 1) { s += __shfl_xor(s, sh); sq += __shfl_xor(sq, sh); }
  __shared__ float red[8];
  int wave = threadIdx.x >> 6, lane = threadIdx.x & 63;
  if (lane == 0) { red[wave] = s; red[4 + wave] = sq; }
  __syncthreads();
  s = red[0] + red[1] + red[2] + red[3];
  sq = red[4] + red[5] + red[6] + red[7];
  float mu = s * (1.0f / DM);
  float var = sq * (1.0f / DM) - mu * mu;
  float inv = rsqrtf(var + LN_EPS);
  f32x4 gv = *(const f32x4*)(g + d);
  f32x4 bv = *(const f32x4*)(b + d);
  f32x4 o;
  o.x = (v.x - mu) * inv * gv.x + bv.x;
  o.y = (v.y - mu) * inv * gv.y + bv.y;
  o.z = (v.z - mu) * inv * gv.z + bv.z;
  o.w = (v.w - mu) * inv * gv.w + bv.w;
  *(f32x4*)(out + (size_t)t * DM + d) = o;
}

extern "C" void kernel_launch(void* const* d_in, const int* in_sizes, int n_in,
                              void* d_out, int out_size, void* d_ws, size_t ws_size,
                              hipStream_t stream)
{
  const int*   tokens = (const int*)d_in[0];
  const float* sym    = (const float*)d_in[1];
  const float* emb    = (const float*)d_in[2];
  const float* gate_w = (const float*)d_in[3];
  const float* gate_b = (const float*)d_in[4];
  const float* w1     = (const float*)d_in[5];
  const float* b1     = (const float*)d_in[6];
  const float* w2     = (const float*)d_in[7];
  const float* b2     = (const float*)d_in[8];
  const float* ln_g   = (const float*)d_in[9];
  const float* ln_b   = (const float*)d_in[10];

  char* ws = (char*)d_ws;
  float* x   = (float*)(ws);                     //  32MB
  u16*   xh  = (u16*)  (ws + 33554432);          //  16MB
  u16*   xl  = (u16*)  (ws + 50331648);          //  16MB
  u16*   hh  = (u16*)  (ws + 67108864);          // 128MB
  u16*   hl  = (u16*)  (ws + 201326592);         // 128MB (L0-G1 only)
  float* y   = (float*)(ws + 201326592);         //  67MB (after pairlogit)
  u16*   wTh = (u16*)  (ws + 335544320);         //  64MB
  u16*   wTl = (u16*)  (ws + 402653184);         //  64MB (L0-G1 only)
  float* W2G = (float*)(ws + 402653184);         //   1MB (after GEMM1-L0)
  float* R   = (float*)(ws + 403701760);         // 512KB
  float* B2G = (float*)(ws + 404226048);         //  256B
  int*   pair_token = (int*)  (ws + 469762048);  //  64KB
  int*   topk_idx   = (int*)  (ws + 469893120);  //  64KB
  float* topk_w     = (float*)(ws + 469958656);  //  64KB
  int*   meta       = (int*)  (ws + 470024192);  //  ~3KB

  embed_kernel<<<T_TOK, 256, 0, stream>>>(tokens, sym, emb, x, xh, xl);

  // ================= layer 0 =================
  gate_kernel<<<T_TOK / 4, 256, 0, stream>>>(x, gate_w, gate_b, topk_idx, topk_w);
  count_kernel<<<T_TOK / 256, 256, 0, stream>>>(topk_idx, meta);
  scan_kernel<<<1, 64, 0, stream>>>(meta);
  scatter_kernel<<<T_TOK / 256, 256, 0, stream>>>(topk_idx, meta, pair_token);

  transpose_kernel<true><<<dim3(DFF / 64, DM / 64, NE), 256, 0, stream>>>(
      w1, wTh, wTl, DM, DFF);
  gemm256_kernel<DM, 3, DFF, true, 1><<<dim3(DFF / 256, MAXTILE), 512, 0, stream>>>(
      xh, xl, wTh, wTl, b1, meta + 8, meta + 32, pair_token, hh, hl, nullptr);

  w2g_kernel<<<NE * DFF / 4, 256, 0, stream>>>(w2, gate_w + (size_t)DM * NE, W2G);
  b2g_kernel<<<16, 256, 0, stream>>>(b2, gate_w + (size_t)DM * NE, B2G);
  pairlogit_kernel<<<NPAIR / 4, 256, 0, stream>>>(hh, hl, meta + 8, W2G, R);

  transpose_kernel<false><<<dim3(DM / 64, DFF / 64, NE), 256, 0, stream>>>(
      w2, wTh, wTl, DFF, DM);
  gemm256_kernel<DFF, 1, DM, false, 2><<<dim3(DM / 256, MAXTILE), 512, 0, stream>>>(
      hh, nullptr, wTh, nullptr, b2, meta + 8, meta + 32, pair_token,
      nullptr, nullptr, y);

  combine0_kernel<<<T_TOK, 256, 0, stream>>>(y, topk_idx, topk_w, xh);

  // ================= layer 1 =================
  gate1_kernel<<<T_TOK / 256, 256, 0, stream>>>(R, B2G, gate_b + NE,
                                                topk_idx, topk_w);
  count_kernel<<<T_TOK / 256, 256, 0, stream>>>(topk_idx, meta);
  scan_kernel<<<1, 64, 0, stream>>>(meta);
  scatter_kernel<<<T_TOK / 256, 256, 0, stream>>>(topk_idx, meta, pair_token);

  transpose_kernel<false><<<dim3(DFF / 64, DM / 64, NE), 256, 0, stream>>>(
      w1 + (size_t)NE * DM * DFF, wTh, wTl, DM, DFF);
  gemm256_kernel<DM, 1, DFF, true, 0><<<dim3(DFF / 256, MAXTILE), 512, 0, stream>>>(
      xh, nullptr, wTh, nullptr, b1 + (size_t)NE * DFF, meta + 8, meta + 32,
      pair_token, hh, nullptr, nullptr);

  transpose_kernel<false><<<dim3(DM / 64, DFF / 64, NE), 256, 0, stream>>>(
      w2 + (size_t)NE * DFF * DM, wTh, wTl, DFF, DM);
  gemm256_kernel<DFF, 1, DM, false, 2><<<dim3(DM / 256, MAXTILE), 512, 0, stream>>>(
      hh, nullptr, wTh, nullptr, b2 + (size_t)NE * DM, meta + 8, meta + 32,
      pair_token, nullptr, nullptr, y);

  combine1_ln_kernel<<<T_TOK, 256, 0, stream>>>(y, topk_idx, topk_w,
                                                ln_g, ln_b, (float*)d_out);
}

// Round 12
// 1617.441 us; speedup vs baseline: 1.1791x; 1.1791x over previous
//
#include <hip/hip_runtime.h>
#include <math.h>

#define T_TOK 8192
#define DM 1024
#define DFF 4096
#define NE 8
#define NPAIR 16384
#define MT256 72
#define MT128 136
#define LN_EPS 1e-5f

typedef __attribute__((ext_vector_type(8))) short bf16x8;
typedef __attribute__((ext_vector_type(4))) float f32x4;
typedef __attribute__((ext_vector_type(4))) unsigned short u16x4;
typedef __attribute__((ext_vector_type(8))) unsigned short u16x8;
typedef unsigned int u32;
typedef unsigned short u16;

__device__ __forceinline__ u16 f2bf(float f) {
  union { float f; u32 u; } v; v.f = f;
  u32 r = (v.u + 0x7fffu + ((v.u >> 16) & 1u)) >> 16;
  return (u16)r;
}
__device__ __forceinline__ float bf2f(u16 h) {
  union { u32 u; float f; } v; v.u = ((u32)h) << 16; return v.f;
}
__device__ __forceinline__ float gelu_exact(float v) {
  return 0.5f * v * (1.0f + erff(v * 0.70710678118654752f));
}
__device__ __forceinline__ float gelu_fast(float v) {
  float u = v * (0.7978845608f + 0.0356774081f * v * v);
  float t = __expf(-2.0f * fabsf(u));
  float th = (1.0f - t) / (1.0f + t);
  th = copysignf(th, u);
  return 0.5f * v * (1.0f + th);
}

__device__ __forceinline__ void gll16(const void* g, void* l) {
  __builtin_amdgcn_global_load_lds(
      (const __attribute__((address_space(1))) u32*)g,
      (__attribute__((address_space(3))) u32*)l, 16, 0, 0);
}

// ---------------- embed ----------------
__global__ __launch_bounds__(256) void embed_kernel(const int* __restrict__ tok,
    const float* __restrict__ sym, const float* __restrict__ emb,
    float* __restrict__ x, u16* __restrict__ xh, u16* __restrict__ xl)
{
  int t = blockIdx.x;
  int b = t >> 11;
  int tk = tok[t];
  int d = threadIdx.x * 4;
  f32x4 e = *(const f32x4*)(emb + (size_t)tk * DM + d);
  f32x4 s = *(const f32x4*)(sym + (size_t)b * DM + d);
  f32x4 v = e + s;
  *(f32x4*)(x + (size_t)t * DM + d) = v;
  u16x4 hv, lv;
#pragma unroll
  for (int j = 0; j < 4; ++j) {
    u16 hb = f2bf(v[j]);
    hv[j] = hb;
    lv[j] = f2bf(v[j] - bf2f(hb));
  }
  *(u16x4*)(xh + (size_t)t * DM + d) = hv;
  *(u16x4*)(xl + (size_t)t * DM + d) = lv;
}

// ---------------- layer-0 gating: f64, top-2 only ----------------
__global__ __launch_bounds__(256) void gate_kernel(const float* __restrict__ x,
    const float* __restrict__ gw, const float* __restrict__ gb,
    int* __restrict__ topk_idx, float* __restrict__ topk_w)
{
  int lane = threadIdx.x & 63;
  int t = blockIdx.x * 4 + (threadIdx.x >> 6);
  const float* xr = x + (size_t)t * DM;
  double a[8] = {0,0,0,0,0,0,0,0};
  for (int i = 0; i < 16; ++i) {
    int d = i * 64 + lane;
    double xv = (double)xr[d];
    const float* g = gw + (size_t)d * NE;
#pragma unroll
    for (int j = 0; j < 8; ++j) a[j] += xv * (double)g[j];
  }
#pragma unroll
  for (int j = 0; j < 8; ++j) {
#pragma unroll
    for (int sh = 32; sh; sh >>= 1) a[j] += __shfl_xor(a[j], sh);
  }
  if (lane == 0) {
#pragma unroll
    for (int j = 0; j < 8; ++j) a[j] += (double)gb[j];
    double m = a[0];
    for (int j = 1; j < 8; ++j) m = a[j] > m ? a[j] : m;
    double p[8], sum = 0.0;
    for (int j = 0; j < 8; ++j) { p[j] = exp(a[j] - m); sum += p[j]; }
    for (int j = 0; j < 8; ++j) p[j] /= sum;
    int j0 = 0; double b0 = p[0];
    for (int j = 1; j < 8; ++j) if (p[j] > b0) { b0 = p[j]; j0 = j; }
    int j1 = (j0 == 0) ? 1 : 0; double b1v = p[j1];
    for (int j = 0; j < 8; ++j) if (j != j0 && p[j] > b1v) { b1v = p[j]; j1 = j; }
    topk_idx[t*2]   = j0; topk_idx[t*2+1] = j1;
    topk_w[t*2]     = (float)b0; topk_w[t*2+1] = (float)b1v;
  }
}

// meta: [0..7]=totals, [8..16]=offsets, [32..103]=tiletab256, [104..239]=tiletab128,
//       [256..511]=blockcnt[32][8], [512..767]=blockbase[32][8]
__global__ __launch_bounds__(256) void count_kernel(const int* __restrict__ topk_idx,
    int* __restrict__ meta)
{
  __shared__ int hist[8];
  int tid = threadIdx.x;
  if (tid < 8) hist[tid] = 0;
  __syncthreads();
  int t = blockIdx.x * 256 + tid;
  atomicAdd(&hist[topk_idx[t*2] & 7], 1);
  atomicAdd(&hist[topk_idx[t*2+1] & 7], 1);
  __syncthreads();
  if (tid < 8) meta[256 + blockIdx.x * 8 + tid] = hist[tid];
}

__global__ __launch_bounds__(64) void scan_kernel(int* __restrict__ meta)
{
  __shared__ int tot[8], off[9], tb2[8], tb1[8];
  int lane = threadIdx.x;
  if (lane < 8) {
    int s = 0;
    for (int b = 0; b < 32; ++b) s += meta[256 + b * 8 + lane];
    tot[lane] = s;
  }
  __syncthreads();
  if (lane == 0) {
    int s = 0, n2 = 0, n1 = 0;
    for (int e = 0; e < 8; ++e) {
      off[e] = s; s += tot[e];
      tb2[e] = n2; n2 += (tot[e] + 255) >> 8;
      tb1[e] = n1; n1 += (tot[e] + 127) >> 7;
    }
    off[8] = s;
    for (int i = n2; i < MT256; ++i) meta[32 + i] = -1;
    for (int i = n1; i < MT128; ++i) meta[104 + i] = -1;
  }
  __syncthreads();
  if (lane < 9) meta[8 + lane] = off[lane];
  if (lane < 8) {
    meta[lane] = tot[lane];
    int n2 = (tot[lane] + 255) >> 8;
    for (int i = 0; i < n2; ++i) meta[32 + tb2[lane] + i] = (lane << 16) | i;
    int n1 = (tot[lane] + 127) >> 7;
    for (int i = 0; i < n1; ++i) meta[104 + tb1[lane] + i] = (lane << 16) | i;
    int run = off[lane];
    for (int b = 0; b < 32; ++b) {
      meta[512 + b * 8 + lane] = run;
      run += meta[256 + b * 8 + lane];
    }
  }
}

__global__ __launch_bounds__(256) void scatter_kernel(int* __restrict__ topk_idx,
    const int* __restrict__ meta, int* __restrict__ pair_token)
{
  __shared__ int hist[8];
  __shared__ int base[8];
  int tid = threadIdx.x;
  if (tid < 8) { hist[tid] = 0; base[tid] = meta[512 + blockIdx.x * 8 + tid]; }
  __syncthreads();
  int t = blockIdx.x * 256 + tid;
#pragma unroll
  for (int k = 0; k < 2; ++k) {
    int e = topk_idx[t*2 + k] & 7;
    int pos = atomicAdd(&hist[e], 1);
    int slot = base[e] + pos;
    pair_token[slot] = t;
    topk_idx[t*2 + k] = e | (slot << 3);
  }
}

// ------------- weight transpose+split: f32 [K][N] -> bf16 hi/lo [N][K] -------------
// vectorized f32x4 global loads (16 B/lane)
template<bool LO>
__global__ __launch_bounds__(256) void transpose_kernel(const float* __restrict__ src,
    u16* __restrict__ dsth, u16* __restrict__ dstl, int K, int N)
{
  __shared__ float tile[64][65];
  int e = blockIdx.z;
  const float* s = src + (size_t)e * K * N;
  size_t dbase = (size_t)e * K * N;
  int n0 = blockIdx.x * 64, k0 = blockIdx.y * 64;
  int tid = threadIdx.x;
#pragma unroll
  for (int j = 0; j < 4; ++j) {
    int kl = j * 16 + (tid >> 4);
    int nn = (tid & 15) * 4;
    f32x4 v = *(const f32x4*)(s + (size_t)(k0 + kl) * N + n0 + nn);
    tile[nn + 0][kl] = v.x;
    tile[nn + 1][kl] = v.y;
    tile[nn + 2][kl] = v.z;
    tile[nn + 3][kl] = v.w;
  }
  __syncthreads();
#pragma unroll
  for (int it = 0; it < 2; ++it) {
    int task = it * 256 + tid;
    int nr = task >> 3;
    int ch = task & 7;
    u16x8 oh, ol;
#pragma unroll
    for (int j = 0; j < 8; ++j) {
      float v = tile[nr][ch*8 + j];
      u16 hb = f2bf(v);
      oh[j] = hb;
      if (LO) ol[j] = f2bf(v - bf2f(hb));
    }
    size_t doff = dbase + (size_t)(n0 + nr) * K + k0 + ch*8;
    *(u16x8*)(dsth + doff) = oh;
    if (LO) *(u16x8*)(dstl + doff) = ol;
  }
}

// ---- W2G[e] = w2[e] @ gw1  ([E][DFF][8], f32) ----
__global__ __launch_bounds__(256) void w2g_kernel(const float* __restrict__ w2,
    const float* __restrict__ gw, float* __restrict__ w2g)
{
  int wid = blockIdx.x * 4 + (threadIdx.x >> 6);
  int lane = threadIdx.x & 63;
  int e = wid >> 12, f = wid & 4095;
  const float* row = w2 + ((size_t)e * DFF + f) * DM;
  float a0=0,a1=0,a2=0,a3=0,a4=0,a5=0,a6=0,a7=0;
  for (int i = 0; i < 4; ++i) {
    int d0 = i * 256 + lane * 4;
    f32x4 xv = *(const f32x4*)(row + d0);
#pragma unroll
    for (int q = 0; q < 4; ++q) {
      const f32x4* gr = (const f32x4*)(gw + (size_t)(d0 + q) * 8);
      f32x4 g0 = gr[0], g1 = gr[1];
      float xq = xv[q];
      a0 += xq*g0.x; a1 += xq*g0.y; a2 += xq*g0.z; a3 += xq*g0.w;
      a4 += xq*g1.x; a5 += xq*g1.y; a6 += xq*g1.z; a7 += xq*g1.w;
    }
  }
  float acc[8] = {a0,a1,a2,a3,a4,a5,a6,a7};
#pragma unroll
  for (int j = 0; j < 8; ++j) {
#pragma unroll
    for (int sh = 32; sh; sh >>= 1) acc[j] += __shfl_xor(acc[j], sh);
  }
  if (lane == 0) {
#pragma unroll
    for (int j = 0; j < 8; ++j) w2g[(size_t)wid * 8 + j] = acc[j];
  }
}

__global__ __launch_bounds__(256) void b2g_kernel(const float* __restrict__ b2,
    const float* __restrict__ gw, float* __restrict__ b2g)
{
  int w = blockIdx.x * 4 + (threadIdx.x >> 6);
  int lane = threadIdx.x & 63;
  int e = w >> 3, j = w & 7;
  float acc = 0.f;
  for (int i = 0; i < 16; ++i) {
    int d = i * 64 + lane;
    acc += b2[(size_t)e * DM + d] * gw[(size_t)d * 8 + j];
  }
#pragma unroll
  for (int sh = 32; sh; sh >>= 1) acc += __shfl_xor(acc, sh);
  if (lane == 0) b2g[w] = acc;
}

// ---- reduceR: R[p][j] = sum over 16 nt partials (fixed order -> deterministic) ----
__global__ __launch_bounds__(256) void reducer_kernel(const float* __restrict__ Rp,
    float* __restrict__ R)
{
  int i = blockIdx.x * 256 + threadIdx.x;  // 0..131071
  float s = 0.f;
#pragma unroll
  for (int nt = 0; nt < 16; ++nt) s += Rp[(size_t)nt * NPAIR * 8 + i];
  R[i] = s;
}

// ---- layer-1 gate ----
__global__ __launch_bounds__(256) void gate1_kernel(const float* __restrict__ R,
    const float* __restrict__ b2g, const float* __restrict__ gb,
    int* __restrict__ topk_idx, float* __restrict__ topk_w)
{
  int t = blockIdx.x * 256 + threadIdx.x;
  int v0 = topk_idx[t*2], v1 = topk_idx[t*2+1];
  int e0 = v0 & 7, e1 = v1 & 7;
  int s0 = v0 >> 3, s1 = v1 >> 3;
  double w0 = (double)topk_w[t*2], w1 = (double)topk_w[t*2+1];
  double a[8];
#pragma unroll
  for (int j = 0; j < 8; ++j)
    a[j] = w0 * ((double)R[(size_t)s0*8+j] + (double)b2g[e0*8+j])
         + w1 * ((double)R[(size_t)s1*8+j] + (double)b2g[e1*8+j])
         + (double)gb[j];
  double m = a[0];
  for (int j = 1; j < 8; ++j) m = a[j] > m ? a[j] : m;
  double p[8], sum = 0.0;
  for (int j = 0; j < 8; ++j) { p[j] = exp(a[j] - m); sum += p[j]; }
  for (int j = 0; j < 8; ++j) p[j] /= sum;
  int j0 = 0; double b0 = p[0];
  for (int j = 1; j < 8; ++j) if (p[j] > b0) { b0 = p[j]; j0 = j; }
  int j1 = (j0 == 0) ? 1 : 0; double b1v = p[j1];
  for (int j = 0; j < 8; ++j) if (j != j0 && p[j] > b1v) { b1v = p[j]; j1 = j; }
  topk_idx[t*2]   = j0; topk_idx[t*2+1] = j1;
  topk_w[t*2]     = (float)b0; topk_w[t*2+1] = (float)b1v;
}

// ====== 256x256 grouped GEMM, BK=64, 8-phase, counted vmcnt (r11-proven loop) ======
// MODE 0: outh = bf16(gelu_fast)            [L1-GEMM1, output path]
// MODE 3: outh = bf16(gelu_exact) + fused R-partials via W2G  [L0-GEMM1]
template<int K0, int NSEG, int NTOT, bool GATHER, int MODE>
__global__ __launch_bounds__(512, 2) void gemm256_kernel(
    const u16* __restrict__ Ah, const u16* __restrict__ Al,
    const u16* __restrict__ Bh, const u16* __restrict__ Bl,
    const float* __restrict__ bias, const int* __restrict__ off,
    const int* __restrict__ tiletab, const int* __restrict__ pair_token,
    u16* __restrict__ outh, const float* __restrict__ W2G,
    float* __restrict__ Rpart)
{
  constexpr int NT = (K0 * NSEG) / 64;
  static_assert(NT >= 2, "");
  const int tt = tiletab[blockIdx.y];
  if (tt < 0) return;
  const int e  = tt >> 16;
  const int mt = tt & 0xffff;
  const int off_e = off[e], off_e1 = off[e + 1];
  const int p0 = off_e + mt * 256;
  const int NX = gridDim.x;
  int bx = blockIdx.x;
  int ntile = ((NX & 7) == 0) ? ((bx & 7) * (NX >> 3) + (bx >> 3)) : bx;
  const int n0 = ntile * 256;

  __shared__ __align__(16) u16 ALs[2][2][8192];
  __shared__ __align__(16) u16 BLs[2][2][8192];

  const int tid  = threadIdx.x;
  const int lane = tid & 63;
  const int wave = tid >> 6;
  const int wm = wave >> 2;
  const int wn = wave & 3;
  const int wbase = tid & 448;

  size_t aoff[2], boff[2];
#pragma unroll
  for (int i = 0; i < 2; ++i) {
    int c = i * 512 + tid;
    int r = c >> 2;
    int cs = (c & 3) ^ ((r >> 1) & 3);
    int idx = p0 + r;
    if (idx >= off_e1) idx = p0;
    int ar = GATHER ? pair_token[idx] : idx;
    aoff[i] = (size_t)ar * K0 + (size_t)(cs * 8);
    boff[i] = ((size_t)e * NTOT + n0 + r) * K0 + (size_t)(cs * 8);
  }

  auto stageA = [&](int t, int kh) {
    int kk = t * 64 + kh * 32;
    int seg = (NSEG == 3) ? (kk >> 10) : 0;
    int kc  = (NSEG == 3) ? (kk & (K0 - 1)) : kk;
    const u16* base = (NSEG == 3 && seg == 1) ? Al : Ah;
    u16* dst = &ALs[t & 1][kh][0];
#pragma unroll
    for (int i = 0; i < 2; ++i)
      gll16(base + aoff[i] + kc, dst + (i * 512 + wbase) * 8);
  };
  auto stageB = [&](int t, int kh) {
    int kk = t * 64 + kh * 32;
    int seg = (NSEG == 3) ? (kk >> 10) : 0;
    int kc  = (NSEG == 3) ? (kk & (K0 - 1)) : kk;
    const u16* base = (NSEG == 3 && seg == 2) ? Bl : Bh;
    u16* dst = &BLs[t & 1][kh][0];
#pragma unroll
    for (int i = 0; i < 2; ++i)
      gll16(base + boff[i] + kc, dst + (i * 512 + wbase) * 8);
  };

  f32x4 acc[8][4];
  const f32x4 fzero = {0.f, 0.f, 0.f, 0.f};
#pragma unroll
  for (int m = 0; m < 8; ++m)
#pragma unroll
    for (int n = 0; n < 4; ++n) acc[m][n] = fzero;

  auto rdA4 = [&](bf16x8* dst, int par, int kh, int mbase) {
    const u16* L = &ALs[par][kh][0];
#pragma unroll
    for (int mf = 0; mf < 4; ++mf) {
      int row = wm * 128 + (mbase + mf) * 16 + (lane & 15);
      dst[mf] = *(const bf16x8*)&L[row * 32 + (((lane >> 4) ^ ((row >> 1) & 3)) << 3)];
    }
  };
  auto rdB4 = [&](bf16x8* dst, int par, int kh) {
    const u16* L = &BLs[par][kh][0];
#pragma unroll
    for (int nf = 0; nf < 4; ++nf) {
      int row = wn * 64 + nf * 16 + (lane & 15);
      dst[nf] = *(const bf16x8*)&L[row * 32 + (((lane >> 4) ^ ((row >> 1) & 3)) << 3)];
    }
  };

#define MMBLK(MB, A4, B4)                                                        \
  {                                                                              \
    __builtin_amdgcn_s_setprio(1);                                               \
    _Pragma("unroll")                                                            \
    for (int mf = 0; mf < 4; ++mf)                                               \
      _Pragma("unroll")                                                          \
      for (int nf = 0; nf < 4; ++nf)                                             \
        acc[(MB) + mf][nf] = __builtin_amdgcn_mfma_f32_16x16x32_bf16(            \
            (A4)[mf], (B4)[nf], acc[(MB) + mf][nf], 0, 0, 0);                    \
    __builtin_amdgcn_s_setprio(0);                                               \
  }

  stageA(0, 0); stageB(0, 0);
  stageA(0, 1); stageB(0, 1);
  stageA(1, 0); stageB(1, 0);
  asm volatile("s_waitcnt vmcnt(8)" ::: "memory");
  __builtin_amdgcn_s_barrier();
  asm volatile("" ::: "memory");

  for (int t = 0; t < NT; ++t) {
    const int par = t & 1;
    bf16x8 bA[4], aA[4], aB[4], bC[4], aC[4], aD[4];
    rdB4(bA, par, 0);
    rdA4(aA, par, 0, 0);
    if (t + 1 < NT) stageA(t + 1, 1);
    __builtin_amdgcn_s_barrier();
    MMBLK(0, aA, bA);
    __builtin_amdgcn_s_barrier();
    rdA4(aB, par, 0, 4);
    if (t + 1 < NT) stageB(t + 1, 1);
    __builtin_amdgcn_s_barrier();
    MMBLK(4, aB, bA);
    if (t + 1 < NT) { asm volatile("s_waitcnt vmcnt(8)" ::: "memory"); }
    else            { asm volatile("s_waitcnt vmcnt(0)" ::: "memory"); }
    __builtin_amdgcn_s_barrier();
    asm volatile("" ::: "memory");
    rdB4(bC, par, 1);
    rdA4(aC, par, 1, 0);
    if (t + 2 < NT) stageA(t + 2, 0);
    __builtin_amdgcn_s_barrier();
    MMBLK(0, aC, bC);
    __builtin_amdgcn_s_barrier();
    rdA4(aD, par, 1, 4);
    if (t + 2 < NT) stageB(t + 2, 0);
    __builtin_amdgcn_s_barrier();
    MMBLK(4, aD, bC);
    if (t + 1 < NT) {
      if (t + 2 < NT) { asm volatile("s_waitcnt vmcnt(8)" ::: "memory"); }
      else            { asm volatile("s_waitcnt vmcnt(4)" ::: "memory"); }
      __builtin_amdgcn_s_barrier();
      asm volatile("" ::: "memory");
    }
  }
#undef MMBLK

  // ---- epilogue ----
  float bv[4];
#pragma unroll
  for (int nf = 0; nf < 4; ++nf)
    bv[nf] = bias[(size_t)e * NTOT + n0 + wn * 64 + nf * 16 + (lane & 15)];

  if constexpr (MODE == 3) {
    __syncthreads();                       // reclaim LDS for Rpt
    float* Rpt = (float*)&ALs[0][0][0];    // [4 wn][256 rows][8] f32 = 32 KB
    f32x4 wg0[4], wg1[4];
#pragma unroll
    for (int nf = 0; nf < 4; ++nf) {
      int col = n0 + wn * 64 + nf * 16 + (lane & 15);
      const float* wp = W2G + ((size_t)e * NTOT + col) * 8;
      wg0[nf] = *(const f32x4*)wp;
      wg1[nf] = *(const f32x4*)(wp + 4);
    }
#pragma unroll
    for (int mf = 0; mf < 8; ++mf) {
      f32x4 pr0[4], pr1[4];
#pragma unroll
      for (int r = 0; r < 4; ++r) { pr0[r] = fzero; pr1[r] = fzero; }
      int rbase = p0 + wm * 128 + mf * 16 + ((lane >> 4) << 2);
#pragma unroll
      for (int nf = 0; nf < 4; ++nf) {
        int col = n0 + wn * 64 + nf * 16 + (lane & 15);
#pragma unroll
        for (int r = 0; r < 4; ++r) {
          float v = gelu_exact(acc[mf][nf][r] + bv[nf]);
          if (rbase + r < off_e1)
            outh[(size_t)(rbase + r) * NTOT + col] = f2bf(v);
          pr0[r] += v * wg0[nf];
          pr1[r] += v * wg1[nf];
        }
      }
#pragma unroll
      for (int r = 0; r < 4; ++r) {
#pragma unroll
        for (int sh = 1; sh < 16; sh <<= 1) {
#pragma unroll
          for (int q = 0; q < 4; ++q) {
            pr0[r][q] += __shfl_xor(pr0[r][q], sh);
            pr1[r][q] += __shfl_xor(pr1[r][q], sh);
          }
        }
        if ((lane & 15) == 0) {
          int rl = wm * 128 + mf * 16 + ((lane >> 4) << 2) + r;
          float* dst = Rpt + ((size_t)(wn * 256 + rl)) * 8;
          *(f32x4*)dst = pr0[r];
          *(f32x4*)(dst + 4) = pr1[r];
        }
      }
    }
    __syncthreads();
    for (int i = tid; i < 256 * 8; i += 512) {
      int rl = i >> 3, j = i & 7;
      float ssum = Rpt[(size_t)(0 * 256 + rl) * 8 + j]
                 + Rpt[(size_t)(1 * 256 + rl) * 8 + j]
                 + Rpt[(size_t)(2 * 256 + rl) * 8 + j]
                 + Rpt[(size_t)(3 * 256 + rl) * 8 + j];
      int p = p0 + rl;
      if (p < off_e1)
        Rpart[((size_t)ntile * NPAIR + p) * 8 + j] = ssum;
    }
  } else {
#pragma unroll
    for (int mf = 0; mf < 8; ++mf) {
      int rbase = p0 + wm * 128 + mf * 16 + ((lane >> 4) << 2);
#pragma unroll
      for (int nf = 0; nf < 4; ++nf) {
        int col = n0 + wn * 64 + nf * 16 + (lane & 15);
#pragma unroll
        for (int r = 0; r < 4; ++r) {
          if (rbase + r < off_e1) {
            float v = gelu_fast(acc[mf][nf][r] + bv[nf]);
            outh[(size_t)(rbase + r) * NTOT + col] = f2bf(v);
          }
        }
      }
    }
  }
}

// ====== 128x128 grouped GEMM, BK=32, ring-2, 32KB LDS (r10-proven) ======
// MODE 2 only: y[slot] = acc + bias (f32)
template<int K0, int NTOT, bool GATHER>
__global__ __launch_bounds__(256, 4) void gemm128_kernel(
    const u16* __restrict__ Ah, const u16* __restrict__ Bh,
    const float* __restrict__ bias, const int* __restrict__ off,
    const int* __restrict__ tiletab, const int* __restrict__ pair_token,
    float* __restrict__ outy)
{
  constexpr int NT = K0 / 32;
  const int tt = tiletab[blockIdx.y];
  if (tt < 0) return;
  const int e  = tt >> 16;
  const int mt = tt & 0xffff;
  const int off_e = off[e], off_e1 = off[e + 1];
  const int p0 = off_e + mt * 128;
  const int NX = gridDim.x;
  int bx = blockIdx.x;
  int ntile = ((NX & 7) == 0) ? ((bx & 7) * (NX >> 3) + (bx >> 3)) : bx;
  const int n0 = ntile * 128;

  __shared__ __align__(16) u16 AL[2][4096];
  __shared__ __align__(16) u16 BL[2][4096];

  const int tid  = threadIdx.x;
  const int lane = tid & 63;
  const int wave = tid >> 6;
  const int wm = wave >> 1, wn = wave & 1;
  const int wbase = tid & 192;

  size_t aoff[2], boff[2];
#pragma unroll
  for (int i = 0; i < 2; ++i) {
    int c = i * 256 + tid;
    int r = c >> 2;
    int cs = (c & 3) ^ ((r >> 1) & 3);
    int idx = p0 + r;
    if (idx >= off_e1) idx = p0;
    int ar = GATHER ? pair_token[idx] : idx;
    aoff[i] = (size_t)ar * K0 + (size_t)(cs * 8);
    boff[i] = ((size_t)e * NTOT + n0 + r) * K0 + (size_t)(cs * 8);
  }

  auto stage = [&](int b, int t) {
    int kc = t * 32;
#pragma unroll
    for (int i = 0; i < 2; ++i) {
      int cb = i * 256 + wbase;
      gll16(Ah + aoff[i] + kc, &AL[b][cb * 8]);
      gll16(Bh + boff[i] + kc, &BL[b][cb * 8]);
    }
  };

  f32x4 acc[4][4];
  const f32x4 fzero = {0.f, 0.f, 0.f, 0.f};
#pragma unroll
  for (int m = 0; m < 4; ++m)
#pragma unroll
    for (int n = 0; n < 4; ++n) acc[m][n] = fzero;

  stage(0, 0);
  __syncthreads();

  int buf = 0;
  for (int t = 0; t < NT; ++t) {
    if (t + 1 < NT) stage(buf ^ 1, t + 1);
    bf16x8 af[4], bf[4];
#pragma unroll
    for (int m = 0; m < 4; ++m) {
      int row = wm * 64 + m * 16 + (lane & 15);
      af[m] = *(const bf16x8*)&AL[buf][row * 32 + (((lane >> 4) ^ ((row >> 1) & 3)) << 3)];
    }
#pragma unroll
    for (int n = 0; n < 4; ++n) {
      int row = wn * 64 + n * 16 + (lane & 15);
      bf[n] = *(const bf16x8*)&BL[buf][row * 32 + (((lane >> 4) ^ ((row >> 1) & 3)) << 3)];
    }
    __builtin_amdgcn_s_setprio(1);
#pragma unroll
    for (int m = 0; m < 4; ++m)
#pragma unroll
      for (int n = 0; n < 4; ++n)
        acc[m][n] = __builtin_amdgcn_mfma_f32_16x16x32_bf16(af[m], bf[n], acc[m][n], 0, 0, 0);
    __builtin_amdgcn_s_setprio(0);
    __syncthreads();
    buf ^= 1;
  }

  float bv[4];
#pragma unroll
  for (int n = 0; n < 4; ++n)
    bv[n] = bias[(size_t)e * NTOT + n0 + wn * 64 + n * 16 + (lane & 15)];

#pragma unroll
  for (int m = 0; m < 4; ++m) {
    int rbase = p0 + wm * 64 + m * 16 + ((lane >> 4) << 2);
#pragma unroll
    for (int n = 0; n < 4; ++n) {
      int col = n0 + wn * 64 + n * 16 + (lane & 15);
#pragma unroll
      for (int r = 0; r < 4; ++r) {
        int rowp = rbase + r;
        if (rowp < off_e1)
          outy[(size_t)rowp * NTOT + col] = acc[m][n][r] + bv[n];
      }
    }
  }
}

// ---------------- combine (layer 0) ----------------
__global__ __launch_bounds__(256) void combine0_kernel(const float* __restrict__ y,
    const int* __restrict__ topk_idx, const float* __restrict__ topk_w,
    u16* __restrict__ xh)
{
  int t = blockIdx.x;
  int d = threadIdx.x * 4;
  int s0 = topk_idx[t*2] >> 3, s1 = topk_idx[t*2 + 1] >> 3;
  float w0 = topk_w[t*2], w1 = topk_w[t*2 + 1];
  f32x4 y0 = *(const f32x4*)(y + (size_t)s0 * DM + d);
  f32x4 y1 = *(const f32x4*)(y + (size_t)s1 * DM + d);
  f32x4 v = y0 * w0 + y1 * w1;
  u16x4 hv;
#pragma unroll
  for (int j = 0; j < 4; ++j) hv[j] = f2bf(v[j]);
  *(u16x4*)(xh + (size_t)t * DM + d) = hv;
}

// ---------------- combine (layer 1) + LayerNorm ----------------
__global__ __launch_bounds__(256) void combine1_ln_kernel(const float* __restrict__ y,
    const int* __restrict__ topk_idx, const float* __restrict__ topk_w,
    const float* __restrict__ g, const float* __restrict__ b, float* __restrict__ out)
{
  int t = blockIdx.x;
  int d = threadIdx.x * 4;
  int s0 = topk_idx[t*2] >> 3, s1 = topk_idx[t*2 + 1] >> 3;
  float w0 = topk_w[t*2], w1 = topk_w[t*2 + 1];
  f32x4 y0 = *(const f32x4*)(y + (size_t)s0 * DM + d);
  f32x4 y1 = *(const f32x4*)(y + (size_t)s1 * DM + d);
  f32x4 v = y0 * w0 + y1 * w1;
  float s = v.x + v.y + v.z + v.w;
  float sq = v.x*v.x + v.y*v.y + v.z*v.z + v.w*v.w;
#pragma unroll
  for (int sh = 32; sh; sh >>= 1) { s += __shfl_xor(s, sh); sq += __shfl_xor(sq, sh); }
  __shared__ float red[8];
  int wave = threadIdx.x >> 6, lane = threadIdx.x & 63;
  if (lane == 0) { red[wave] = s; red[4 + wave] = sq; }
  __syncthreads();
  s = red[0] + red[1] + red[2] + red[3];
  sq = red[4] + red[5] + red[6] + red[7];
  float mu = s * (1.0f / DM);
  float var = sq * (1.0f / DM) - mu * mu;
  float inv = rsqrtf(var + LN_EPS);
  f32x4 gv = *(const f32x4*)(g + d);
  f32x4 bv = *(const f32x4*)(b + d);
  f32x4 o;
  o.x = (v.x - mu) * inv * gv.x + bv.x;
  o.y = (v.y - mu) * inv * gv.y + bv.y;
  o.z = (v.z - mu) * inv * gv.z + bv.z;
  o.w = (v.w - mu) * inv * gv.w + bv.w;
  *(f32x4*)(out + (size_t)t * DM + d) = o;
}

extern "C" void kernel_launch(void* const* d_in, const int* in_sizes, int n_in,
                              void* d_out, int out_size, void* d_ws, size_t ws_size,
                              hipStream_t stream)
{
  const int*   tokens = (const int*)d_in[0];
  const float* sym    = (const float*)d_in[1];
  const float* emb    = (const float*)d_in[2];
  const float* gate_w = (const float*)d_in[3];
  const float* gate_b = (const float*)d_in[4];
  const float* w1     = (const float*)d_in[5];
  const float* b1     = (const float*)d_in[6];
  const float* w2     = (const float*)d_in[7];
  const float* b2     = (const float*)d_in[8];
  const float* ln_g   = (const float*)d_in[9];
  const float* ln_b   = (const float*)d_in[10];

  char* ws = (char*)d_ws;
  float* x   = (float*)(ws);                     //  32MB f32 x
  u16*   xh  = (u16*)  (ws + 33554432);          //  16MB
  u16*   xl  = (u16*)  (ws + 50331648);          //  16MB
  u16*   hh  = (u16*)  (ws + 67108864);          // 128MB [16384][4096] bf16
  // --- former hl region [201326592, 335544320), repurposed: ---
  float* W2G   = (float*)(ws + 201326592);       //   1MB [8][4096][8]
  float* Rpart = (float*)(ws + 202375168);       //  16MB [16][16384][8]
  float* B2G   = (float*)(ws + 219152384);       //  256B
  float* R     = (float*)(ws + 219152640);       // 512KB [16384][8]
  float* y     = (float*)(ws + 219676928);       //  67MB [16384][1024]
  // ------------------------------------------------------------
  u16*   wTh = (u16*)  (ws + 335544320);         //  64MB
  u16*   wTl = (u16*)  (ws + 402653184);         //  64MB (L0-GEMM1 only)
  int*   pair_token = (int*)  (ws + 469762048);  //  64KB
  int*   topk_idx   = (int*)  (ws + 469893120);  //  64KB (expert | slot<<3)
  float* topk_w     = (float*)(ws + 469958656);  //  64KB
  int*   meta       = (int*)  (ws + 470024192);  //  3KB

  embed_kernel<<<T_TOK, 256, 0, stream>>>(tokens, sym, emb, x, xh, xl);

  // ================= layer 0 =================
  gate_kernel<<<T_TOK / 4, 256, 0, stream>>>(x, gate_w, gate_b, topk_idx, topk_w);
  count_kernel<<<T_TOK / 256, 256, 0, stream>>>(topk_idx, meta);
  scan_kernel<<<1, 64, 0, stream>>>(meta);
  scatter_kernel<<<T_TOK / 256, 256, 0, stream>>>(topk_idx, meta, pair_token);

  w2g_kernel<<<NE * DFF / 4, 256, 0, stream>>>(w2, gate_w + (size_t)DM * NE, W2G);
  b2g_kernel<<<16, 256, 0, stream>>>(b2, gate_w + (size_t)DM * NE, B2G);

  transpose_kernel<true><<<dim3(DFF / 64, DM / 64, NE), 256, 0, stream>>>(
      w1, wTh, wTl, DM, DFF);
  gemm256_kernel<DM, 3, DFF, true, 3><<<dim3(DFF / 256, MT256), 512, 0, stream>>>(
      xh, xl, wTh, wTl, b1, meta + 8, meta + 32, pair_token, hh, W2G, Rpart);

  reducer_kernel<<<NPAIR * 8 / 256, 256, 0, stream>>>(Rpart, R);

  transpose_kernel<false><<<dim3(DM / 64, DFF / 64, NE), 256, 0, stream>>>(
      w2, wTh, nullptr, DFF, DM);
  gemm128_kernel<DFF, DM, false><<<dim3(DM / 128, MT128), 256, 0, stream>>>(
      hh, wTh, b2, meta + 8, meta + 104, pair_token, y);

  combine0_kernel<<<T_TOK, 256, 0, stream>>>(y, topk_idx, topk_w, xh);

  // ================= layer 1 =================
  gate1_kernel<<<T_TOK / 256, 256, 0, stream>>>(R, B2G, gate_b + NE,
                                                topk_idx, topk_w);
  count_kernel<<<T_TOK / 256, 256, 0, stream>>>(topk_idx, meta);
  scan_kernel<<<1, 64, 0, stream>>>(meta);
  scatter_kernel<<<T_TOK / 256, 256, 0, stream>>>(topk_idx, meta, pair_token);

  transpose_kernel<false><<<dim3(DFF / 64, DM / 64, NE), 256, 0, stream>>>(
      w1 + (size_t)NE * DM * DFF, wTh, nullptr, DM, DFF);
  gemm256_kernel<DM, 1, DFF, true, 0><<<dim3(DFF / 256, MT256), 512, 0, stream>>>(
      xh, nullptr, wTh, nullptr, b1 + (size_t)NE * DFF, meta + 8, meta + 32,
      pair_token, hh, nullptr, nullptr);

  transpose_kernel<false><<<dim3(DM / 64, DFF / 64, NE), 256, 0, stream>>>(
      w2 + (size_t)NE * DFF * DM, wTh, nullptr, DFF, DM);
  gemm128_kernel<DFF, DM, false><<<dim3(DM / 128, MT128), 256, 0, stream>>>(
      hh, wTh, b2 + (size_t)NE * DM, meta + 8, meta + 104, pair_token, y);

  combine1_ln_kernel<<<T_TOK, 256, 0, stream>>>(y, topk_idx, topk_w,
                                                ln_g, ln_b, (float*)d_out);
}

// Round 13
// 1578.474 us; speedup vs baseline: 1.2082x; 1.0247x over previous
//
#include <hip/hip_runtime.h>
#include <math.h>

#define T_TOK 8192
#define DM 1024
#define DFF 4096
#define NE 8
#define NPAIR 16384
#define MT256 72
#define MT128 136
#define LN_EPS 1e-5f

typedef __attribute__((ext_vector_type(8))) short bf16x8;
typedef __attribute__((ext_vector_type(4))) float f32x4;
typedef __attribute__((ext_vector_type(4))) unsigned short u16x4;
typedef __attribute__((ext_vector_type(8))) unsigned short u16x8;
typedef unsigned int u32;
typedef unsigned short u16;

__device__ __forceinline__ u16 f2bf(float f) {
  union { float f; u32 u; } v; v.f = f;
  u32 r = (v.u + 0x7fffu + ((v.u >> 16) & 1u)) >> 16;
  return (u16)r;
}
__device__ __forceinline__ float bf2f(u16 h) {
  union { u32 u; float f; } v; v.u = ((u32)h) << 16; return v.f;
}
__device__ __forceinline__ float gelu_exact(float v) {
  return 0.5f * v * (1.0f + erff(v * 0.70710678118654752f));
}
__device__ __forceinline__ float gelu_fast(float v) {
  float u = v * (0.7978845608f + 0.0356774081f * v * v);
  float t = __expf(-2.0f * fabsf(u));
  float th = (1.0f - t) / (1.0f + t);
  th = copysignf(th, u);
  return 0.5f * v * (1.0f + th);
}

__device__ __forceinline__ void gll16(const void* g, void* l) {
  __builtin_amdgcn_global_load_lds(
      (const __attribute__((address_space(1))) u32*)g,
      (__attribute__((address_space(3))) u32*)l, 16, 0, 0);
}

// -------- fused embed + layer-0 gate: xh/xl + f64 top-2 routing, no x buffer --------
__global__ __launch_bounds__(256) void embed_gate_kernel(const int* __restrict__ tok,
    const float* __restrict__ sym, const float* __restrict__ emb,
    const float* __restrict__ gw, const float* __restrict__ gb,
    u16* __restrict__ xh, u16* __restrict__ xl,
    int* __restrict__ topk_idx, float* __restrict__ topk_w)
{
  int t = blockIdx.x;
  int b = t >> 11;
  int tk = tok[t];
  int d = threadIdx.x * 4;
  f32x4 e = *(const f32x4*)(emb + (size_t)tk * DM + d);
  f32x4 s = *(const f32x4*)(sym + (size_t)b * DM + d);
  f32x4 v = e + s;
  u16x4 hv, lv;
#pragma unroll
  for (int j = 0; j < 4; ++j) {
    u16 hb = f2bf(v[j]);
    hv[j] = hb;
    lv[j] = f2bf(v[j] - bf2f(hb));
  }
  *(u16x4*)(xh + (size_t)t * DM + d) = hv;
  *(u16x4*)(xl + (size_t)t * DM + d) = lv;

  double a[8] = {0,0,0,0,0,0,0,0};
#pragma unroll
  for (int q = 0; q < 4; ++q) {
    const f32x4* gr = (const f32x4*)(gw + (size_t)(d + q) * 8);
    f32x4 g0 = gr[0], g1 = gr[1];
    double xv = (double)v[q];
    a[0] += xv*(double)g0.x; a[1] += xv*(double)g0.y;
    a[2] += xv*(double)g0.z; a[3] += xv*(double)g0.w;
    a[4] += xv*(double)g1.x; a[5] += xv*(double)g1.y;
    a[6] += xv*(double)g1.z; a[7] += xv*(double)g1.w;
  }
#pragma unroll
  for (int j = 0; j < 8; ++j) {
#pragma unroll
    for (int sh = 32; sh; sh >>= 1) a[j] += __shfl_xor(a[j], sh);
  }
  __shared__ double red[4][8];
  int wave = threadIdx.x >> 6, lane = threadIdx.x & 63;
  if (lane == 0) {
#pragma unroll
    for (int j = 0; j < 8; ++j) red[wave][j] = a[j];
  }
  __syncthreads();
  if (threadIdx.x == 0) {
    double lg[8];
#pragma unroll
    for (int j = 0; j < 8; ++j)
      lg[j] = red[0][j] + red[1][j] + red[2][j] + red[3][j] + (double)gb[j];
    double m = lg[0];
    for (int j = 1; j < 8; ++j) m = lg[j] > m ? lg[j] : m;
    double p[8], sum = 0.0;
    for (int j = 0; j < 8; ++j) { p[j] = exp(lg[j] - m); sum += p[j]; }
    for (int j = 0; j < 8; ++j) p[j] /= sum;
    int j0 = 0; double b0 = p[0];
    for (int j = 1; j < 8; ++j) if (p[j] > b0) { b0 = p[j]; j0 = j; }
    int j1 = (j0 == 0) ? 1 : 0; double b1v = p[j1];
    for (int j = 0; j < 8; ++j) if (j != j0 && p[j] > b1v) { b1v = p[j]; j1 = j; }
    topk_idx[t*2]   = j0; topk_idx[t*2+1] = j1;
    topk_w[t*2]     = (float)b0; topk_w[t*2+1] = (float)b1v;
  }
}

// meta: [0..7]=totals, [8..16]=offsets, [32..103]=tiletab256, [104..239]=tiletab128,
//       [256..511]=blockcnt[32][8], [512..767]=blockbase[32][8]
__global__ __launch_bounds__(256) void count_kernel(const int* __restrict__ topk_idx,
    int* __restrict__ meta)
{
  __shared__ int hist[8];
  int tid = threadIdx.x;
  if (tid < 8) hist[tid] = 0;
  __syncthreads();
  int t = blockIdx.x * 256 + tid;
  atomicAdd(&hist[topk_idx[t*2] & 7], 1);
  atomicAdd(&hist[topk_idx[t*2+1] & 7], 1);
  __syncthreads();
  if (tid < 8) meta[256 + blockIdx.x * 8 + tid] = hist[tid];
}

__global__ __launch_bounds__(64) void scan_kernel(int* __restrict__ meta)
{
  __shared__ int tot[8], off[9], tb2[8], tb1[8];
  int lane = threadIdx.x;
  if (lane < 8) {
    int s = 0;
    for (int b = 0; b < 32; ++b) s += meta[256 + b * 8 + lane];
    tot[lane] = s;
  }
  __syncthreads();
  if (lane == 0) {
    int s = 0, n2 = 0, n1 = 0;
    for (int e = 0; e < 8; ++e) {
      off[e] = s; s += tot[e];
      tb2[e] = n2; n2 += (tot[e] + 255) >> 8;
      tb1[e] = n1; n1 += (tot[e] + 127) >> 7;
    }
    off[8] = s;
    for (int i = n2; i < MT256; ++i) meta[32 + i] = -1;
    for (int i = n1; i < MT128; ++i) meta[104 + i] = -1;
  }
  __syncthreads();
  if (lane < 9) meta[8 + lane] = off[lane];
  if (lane < 8) {
    meta[lane] = tot[lane];
    int n2 = (tot[lane] + 255) >> 8;
    for (int i = 0; i < n2; ++i) meta[32 + tb2[lane] + i] = (lane << 16) | i;
    int n1 = (tot[lane] + 127) >> 7;
    for (int i = 0; i < n1; ++i) meta[104 + tb1[lane] + i] = (lane << 16) | i;
    int run = off[lane];
    for (int b = 0; b < 32; ++b) {
      meta[512 + b * 8 + lane] = run;
      run += meta[256 + b * 8 + lane];
    }
  }
}

__global__ __launch_bounds__(256) void scatter_kernel(int* __restrict__ topk_idx,
    const int* __restrict__ meta, int* __restrict__ pair_token)
{
  __shared__ int hist[8];
  __shared__ int base[8];
  int tid = threadIdx.x;
  if (tid < 8) { hist[tid] = 0; base[tid] = meta[512 + blockIdx.x * 8 + tid]; }
  __syncthreads();
  int t = blockIdx.x * 256 + tid;
#pragma unroll
  for (int k = 0; k < 2; ++k) {
    int e = topk_idx[t*2 + k] & 7;
    int pos = atomicAdd(&hist[e], 1);
    int slot = base[e] + pos;
    pair_token[slot] = t;
    topk_idx[t*2 + k] = e | (slot << 3);
  }
}

// ------------- weight transpose+split: f32 [K][N] -> bf16 hi/lo [N][K] -------------
template<bool LO>
__global__ __launch_bounds__(256) void transpose_kernel(const float* __restrict__ src,
    u16* __restrict__ dsth, u16* __restrict__ dstl, int K, int N)
{
  __shared__ float tile[64][65];
  int e = blockIdx.z;
  const float* s = src + (size_t)e * K * N;
  size_t dbase = (size_t)e * K * N;
  int n0 = blockIdx.x * 64, k0 = blockIdx.y * 64;
  int tid = threadIdx.x;
#pragma unroll
  for (int j = 0; j < 4; ++j) {
    int kl = j * 16 + (tid >> 4);
    int nn = (tid & 15) * 4;
    f32x4 v = *(const f32x4*)(s + (size_t)(k0 + kl) * N + n0 + nn);
    tile[nn + 0][kl] = v.x;
    tile[nn + 1][kl] = v.y;
    tile[nn + 2][kl] = v.z;
    tile[nn + 3][kl] = v.w;
  }
  __syncthreads();
#pragma unroll
  for (int it = 0; it < 2; ++it) {
    int task = it * 256 + tid;
    int nr = task >> 3;
    int ch = task & 7;
    u16x8 oh, ol;
#pragma unroll
    for (int j = 0; j < 8; ++j) {
      float v = tile[nr][ch*8 + j];
      u16 hb = f2bf(v);
      oh[j] = hb;
      if (LO) ol[j] = f2bf(v - bf2f(hb));
    }
    size_t doff = dbase + (size_t)(n0 + nr) * K + k0 + ch*8;
    *(u16x8*)(dsth + doff) = oh;
    if (LO) *(u16x8*)(dstl + doff) = ol;
  }
}

// ---- W2G[e] = w2[e] @ gw1  ([E][DFF][8], f32) ----
__global__ __launch_bounds__(256) void w2g_kernel(const float* __restrict__ w2,
    const float* __restrict__ gw, float* __restrict__ w2g)
{
  int wid = blockIdx.x * 4 + (threadIdx.x >> 6);
  int lane = threadIdx.x & 63;
  int e = wid >> 12, f = wid & 4095;
  const float* row = w2 + ((size_t)e * DFF + f) * DM;
  float a0=0,a1=0,a2=0,a3=0,a4=0,a5=0,a6=0,a7=0;
  for (int i = 0; i < 4; ++i) {
    int d0 = i * 256 + lane * 4;
    f32x4 xv = *(const f32x4*)(row + d0);
#pragma unroll
    for (int q = 0; q < 4; ++q) {
      const f32x4* gr = (const f32x4*)(gw + (size_t)(d0 + q) * 8);
      f32x4 g0 = gr[0], g1 = gr[1];
      float xq = xv[q];
      a0 += xq*g0.x; a1 += xq*g0.y; a2 += xq*g0.z; a3 += xq*g0.w;
      a4 += xq*g1.x; a5 += xq*g1.y; a6 += xq*g1.z; a7 += xq*g1.w;
    }
  }
  float acc[8] = {a0,a1,a2,a3,a4,a5,a6,a7};
#pragma unroll
  for (int j = 0; j < 8; ++j) {
#pragma unroll
    for (int sh = 32; sh; sh >>= 1) acc[j] += __shfl_xor(acc[j], sh);
  }
  if (lane == 0) {
#pragma unroll
    for (int j = 0; j < 8; ++j) w2g[(size_t)wid * 8 + j] = acc[j];
  }
}

__global__ __launch_bounds__(256) void b2g_kernel(const float* __restrict__ b2,
    const float* __restrict__ gw, float* __restrict__ b2g)
{
  int w = blockIdx.x * 4 + (threadIdx.x >> 6);
  int lane = threadIdx.x & 63;
  int e = w >> 3, j = w & 7;
  float acc = 0.f;
  for (int i = 0; i < 16; ++i) {
    int d = i * 64 + lane;
    acc += b2[(size_t)e * DM + d] * gw[(size_t)d * 8 + j];
  }
#pragma unroll
  for (int sh = 32; sh; sh >>= 1) acc += __shfl_xor(acc, sh);
  if (lane == 0) b2g[w] = acc;
}

// ---- reduceR: R[p][j] = sum over 16 nt partials (fixed order -> deterministic) ----
__global__ __launch_bounds__(256) void reducer_kernel(const float* __restrict__ Rp,
    float* __restrict__ R)
{
  int i = blockIdx.x * 256 + threadIdx.x;
  float s = 0.f;
#pragma unroll
  for (int nt = 0; nt < 16; ++nt) s += Rp[(size_t)nt * NPAIR * 8 + i];
  R[i] = s;
}

// ---- layer-1 gate ----
__global__ __launch_bounds__(256) void gate1_kernel(const float* __restrict__ R,
    const float* __restrict__ b2g, const float* __restrict__ gb,
    int* __restrict__ topk_idx, float* __restrict__ topk_w)
{
  int t = blockIdx.x * 256 + threadIdx.x;
  int v0 = topk_idx[t*2], v1 = topk_idx[t*2+1];
  int e0 = v0 & 7, e1 = v1 & 7;
  int s0 = v0 >> 3, s1 = v1 >> 3;
  double w0 = (double)topk_w[t*2], w1 = (double)topk_w[t*2+1];
  double a[8];
#pragma unroll
  for (int j = 0; j < 8; ++j)
    a[j] = w0 * ((double)R[(size_t)s0*8+j] + (double)b2g[e0*8+j])
         + w1 * ((double)R[(size_t)s1*8+j] + (double)b2g[e1*8+j])
         + (double)gb[j];
  double m = a[0];
  for (int j = 1; j < 8; ++j) m = a[j] > m ? a[j] : m;
  double p[8], sum = 0.0;
  for (int j = 0; j < 8; ++j) { p[j] = exp(a[j] - m); sum += p[j]; }
  for (int j = 0; j < 8; ++j) p[j] /= sum;
  int j0 = 0; double b0 = p[0];
  for (int j = 1; j < 8; ++j) if (p[j] > b0) { b0 = p[j]; j0 = j; }
  int j1 = (j0 == 0) ? 1 : 0; double b1v = p[j1];
  for (int j = 0; j < 8; ++j) if (j != j0 && p[j] > b1v) { b1v = p[j]; j1 = j; }
  topk_idx[t*2]   = j0; topk_idx[t*2+1] = j1;
  topk_w[t*2]     = (float)b0; topk_w[t*2+1] = (float)b1v;
}

// ====== 256x256 grouped GEMM, BK=64, 8-phase, counted vmcnt ======
// MODE 3 only now: outh = bf16(gelu_exact) + fused R-partials via W2G  [L0-GEMM1]
template<int K0, int NSEG, int NTOT, bool GATHER>
__global__ __launch_bounds__(512, 2) void gemm256_kernel(
    const u16* __restrict__ Ah, const u16* __restrict__ Al,
    const u16* __restrict__ Bh, const u16* __restrict__ Bl,
    const float* __restrict__ bias, const int* __restrict__ off,
    const int* __restrict__ tiletab, const int* __restrict__ pair_token,
    u16* __restrict__ outh, const float* __restrict__ W2G,
    float* __restrict__ Rpart)
{
  constexpr int NT = (K0 * NSEG) / 64;
  static_assert(NT >= 2, "");
  const int tt = tiletab[blockIdx.y];
  if (tt < 0) return;
  const int e  = tt >> 16;
  const int mt = tt & 0xffff;
  const int off_e = off[e], off_e1 = off[e + 1];
  const int p0 = off_e + mt * 256;
  const int NX = gridDim.x;
  int bx = blockIdx.x;
  int ntile = ((NX & 7) == 0) ? ((bx & 7) * (NX >> 3) + (bx >> 3)) : bx;
  const int n0 = ntile * 256;

  __shared__ __align__(16) u16 ALs[2][2][8192];
  __shared__ __align__(16) u16 BLs[2][2][8192];

  const int tid  = threadIdx.x;
  const int lane = tid & 63;
  const int wave = tid >> 6;
  const int wm = wave >> 2;
  const int wn = wave & 3;
  const int wbase = tid & 448;

  size_t aoff[2], boff[2];
#pragma unroll
  for (int i = 0; i < 2; ++i) {
    int c = i * 512 + tid;
    int r = c >> 2;
    int cs = (c & 3) ^ ((r >> 1) & 3);
    int idx = p0 + r;
    if (idx >= off_e1) idx = p0;
    int ar = GATHER ? pair_token[idx] : idx;
    aoff[i] = (size_t)ar * K0 + (size_t)(cs * 8);
    boff[i] = ((size_t)e * NTOT + n0 + r) * K0 + (size_t)(cs * 8);
  }

  auto stageA = [&](int t, int kh) {
    int kk = t * 64 + kh * 32;
    int seg = (NSEG == 3) ? (kk >> 10) : 0;
    int kc  = (NSEG == 3) ? (kk & (K0 - 1)) : kk;
    const u16* base = (NSEG == 3 && seg == 1) ? Al : Ah;
    u16* dst = &ALs[t & 1][kh][0];
#pragma unroll
    for (int i = 0; i < 2; ++i)
      gll16(base + aoff[i] + kc, dst + (i * 512 + wbase) * 8);
  };
  auto stageB = [&](int t, int kh) {
    int kk = t * 64 + kh * 32;
    int seg = (NSEG == 3) ? (kk >> 10) : 0;
    int kc  = (NSEG == 3) ? (kk & (K0 - 1)) : kk;
    const u16* base = (NSEG == 3 && seg == 2) ? Bl : Bh;
    u16* dst = &BLs[t & 1][kh][0];
#pragma unroll
    for (int i = 0; i < 2; ++i)
      gll16(base + boff[i] + kc, dst + (i * 512 + wbase) * 8);
  };

  f32x4 acc[8][4];
  const f32x4 fzero = {0.f, 0.f, 0.f, 0.f};
#pragma unroll
  for (int m = 0; m < 8; ++m)
#pragma unroll
    for (int n = 0; n < 4; ++n) acc[m][n] = fzero;

  auto rdA4 = [&](bf16x8* dst, int par, int kh, int mbase) {
    const u16* L = &ALs[par][kh][0];
#pragma unroll
    for (int mf = 0; mf < 4; ++mf) {
      int row = wm * 128 + (mbase + mf) * 16 + (lane & 15);
      dst[mf] = *(const bf16x8*)&L[row * 32 + (((lane >> 4) ^ ((row >> 1) & 3)) << 3)];
    }
  };
  auto rdB4 = [&](bf16x8* dst, int par, int kh) {
    const u16* L = &BLs[par][kh][0];
#pragma unroll
    for (int nf = 0; nf < 4; ++nf) {
      int row = wn * 64 + nf * 16 + (lane & 15);
      dst[nf] = *(const bf16x8*)&L[row * 32 + (((lane >> 4) ^ ((row >> 1) & 3)) << 3)];
    }
  };

#define MMBLK(MB, A4, B4)                                                        \
  {                                                                              \
    __builtin_amdgcn_s_setprio(1);                                               \
    _Pragma("unroll")                                                            \
    for (int mf = 0; mf < 4; ++mf)                                               \
      _Pragma("unroll")                                                          \
      for (int nf = 0; nf < 4; ++nf)                                             \
        acc[(MB) + mf][nf] = __builtin_amdgcn_mfma_f32_16x16x32_bf16(            \
            (A4)[mf], (B4)[nf], acc[(MB) + mf][nf], 0, 0, 0);                    \
    __builtin_amdgcn_s_setprio(0);                                               \
  }

  stageA(0, 0); stageB(0, 0);
  stageA(0, 1); stageB(0, 1);
  stageA(1, 0); stageB(1, 0);
  asm volatile("s_waitcnt vmcnt(8)" ::: "memory");
  __builtin_amdgcn_s_barrier();
  asm volatile("" ::: "memory");

  for (int t = 0; t < NT; ++t) {
    const int par = t & 1;
    bf16x8 bA[4], aA[4], aB[4], bC[4], aC[4], aD[4];
    rdB4(bA, par, 0);
    rdA4(aA, par, 0, 0);
    if (t + 1 < NT) stageA(t + 1, 1);
    __builtin_amdgcn_s_barrier();
    MMBLK(0, aA, bA);
    __builtin_amdgcn_s_barrier();
    rdA4(aB, par, 0, 4);
    if (t + 1 < NT) stageB(t + 1, 1);
    __builtin_amdgcn_s_barrier();
    MMBLK(4, aB, bA);
    if (t + 1 < NT) { asm volatile("s_waitcnt vmcnt(8)" ::: "memory"); }
    else            { asm volatile("s_waitcnt vmcnt(0)" ::: "memory"); }
    __builtin_amdgcn_s_barrier();
    asm volatile("" ::: "memory");
    rdB4(bC, par, 1);
    rdA4(aC, par, 1, 0);
    if (t + 2 < NT) stageA(t + 2, 0);
    __builtin_amdgcn_s_barrier();
    MMBLK(0, aC, bC);
    __builtin_amdgcn_s_barrier();
    rdA4(aD, par, 1, 4);
    if (t + 2 < NT) stageB(t + 2, 0);
    __builtin_amdgcn_s_barrier();
    MMBLK(4, aD, bC);
    if (t + 1 < NT) {
      if (t + 2 < NT) { asm volatile("s_waitcnt vmcnt(8)" ::: "memory"); }
      else            { asm volatile("s_waitcnt vmcnt(4)" ::: "memory"); }
      __builtin_amdgcn_s_barrier();
      asm volatile("" ::: "memory");
    }
  }
#undef MMBLK

  float bv[4];
#pragma unroll
  for (int nf = 0; nf < 4; ++nf)
    bv[nf] = bias[(size_t)e * NTOT + n0 + wn * 64 + nf * 16 + (lane & 15)];

  __syncthreads();                       // reclaim LDS for Rpt
  float* Rpt = (float*)&ALs[0][0][0];    // [4 wn][256 rows][8] f32 = 32 KB
  f32x4 wg0[4], wg1[4];
#pragma unroll
  for (int nf = 0; nf < 4; ++nf) {
    int col = n0 + wn * 64 + nf * 16 + (lane & 15);
    const float* wp = W2G + ((size_t)e * NTOT + col) * 8;
    wg0[nf] = *(const f32x4*)wp;
    wg1[nf] = *(const f32x4*)(wp + 4);
  }
#pragma unroll
  for (int mf = 0; mf < 8; ++mf) {
    f32x4 pr0[4], pr1[4];
#pragma unroll
    for (int r = 0; r < 4; ++r) { pr0[r] = fzero; pr1[r] = fzero; }
    int rbase = p0 + wm * 128 + mf * 16 + ((lane >> 4) << 2);
#pragma unroll
    for (int nf = 0; nf < 4; ++nf) {
      int col = n0 + wn * 64 + nf * 16 + (lane & 15);
#pragma unroll
      for (int r = 0; r < 4; ++r) {
        float v = gelu_exact(acc[mf][nf][r] + bv[nf]);
        if (rbase + r < off_e1)
          outh[(size_t)(rbase + r) * NTOT + col] = f2bf(v);
        pr0[r] += v * wg0[nf];
        pr1[r] += v * wg1[nf];
      }
    }
#pragma unroll
    for (int r = 0; r < 4; ++r) {
#pragma unroll
      for (int sh = 1; sh < 16; sh <<= 1) {
#pragma unroll
        for (int q = 0; q < 4; ++q) {
          pr0[r][q] += __shfl_xor(pr0[r][q], sh);
          pr1[r][q] += __shfl_xor(pr1[r][q], sh);
        }
      }
      if ((lane & 15) == 0) {
        int rl = wm * 128 + mf * 16 + ((lane >> 4) << 2) + r;
        float* dst = Rpt + ((size_t)(wn * 256 + rl)) * 8;
        *(f32x4*)dst = pr0[r];
        *(f32x4*)(dst + 4) = pr1[r];
      }
    }
  }
  __syncthreads();
  for (int i = tid; i < 256 * 8; i += 512) {
    int rl = i >> 3, j = i & 7;
    float ssum = Rpt[(size_t)(0 * 256 + rl) * 8 + j]
               + Rpt[(size_t)(1 * 256 + rl) * 8 + j]
               + Rpt[(size_t)(2 * 256 + rl) * 8 + j]
               + Rpt[(size_t)(3 * 256 + rl) * 8 + j];
    int p = p0 + rl;
    if (p < off_e1)
      Rpart[((size_t)ntile * NPAIR + p) * 8 + j] = ssum;
  }
}

// ====== 128x128 grouped GEMM, BK=32, ring-2, 32KB LDS ======
// MODE 0: outh = bf16(gelu_fast)   [L1-GEMM1]
// MODE 2: outy = bf16(acc + bias)  [GEMM2s -> yb]
template<int K0, int NTOT, bool GATHER, int MODE>
__global__ __launch_bounds__(256, 4) void gemm128_kernel(
    const u16* __restrict__ Ah, const u16* __restrict__ Bh,
    const float* __restrict__ bias, const int* __restrict__ off,
    const int* __restrict__ tiletab, const int* __restrict__ pair_token,
    u16* __restrict__ outp)
{
  constexpr int NT = K0 / 32;
  const int tt = tiletab[blockIdx.y];
  if (tt < 0) return;
  const int e  = tt >> 16;
  const int mt = tt & 0xffff;
  const int off_e = off[e], off_e1 = off[e + 1];
  const int p0 = off_e + mt * 128;
  const int NX = gridDim.x;
  int bx = blockIdx.x;
  int ntile = ((NX & 7) == 0) ? ((bx & 7) * (NX >> 3) + (bx >> 3)) : bx;
  const int n0 = ntile * 128;

  __shared__ __align__(16) u16 AL[2][4096];
  __shared__ __align__(16) u16 BL[2][4096];

  const int tid  = threadIdx.x;
  const int lane = tid & 63;
  const int wave = tid >> 6;
  const int wm = wave >> 1, wn = wave & 1;
  const int wbase = tid & 192;

  size_t aoff[2], boff[2];
#pragma unroll
  for (int i = 0; i < 2; ++i) {
    int c = i * 256 + tid;
    int r = c >> 2;
    int cs = (c & 3) ^ ((r >> 1) & 3);
    int idx = p0 + r;
    if (idx >= off_e1) idx = p0;
    int ar = GATHER ? pair_token[idx] : idx;
    aoff[i] = (size_t)ar * K0 + (size_t)(cs * 8);
    boff[i] = ((size_t)e * NTOT + n0 + r) * K0 + (size_t)(cs * 8);
  }

  auto stage = [&](int b, int t) {
    int kc = t * 32;
#pragma unroll
    for (int i = 0; i < 2; ++i) {
      int cb = i * 256 + wbase;
      gll16(Ah + aoff[i] + kc, &AL[b][cb * 8]);
      gll16(Bh + boff[i] + kc, &BL[b][cb * 8]);
    }
  };

  f32x4 acc[4][4];
  const f32x4 fzero = {0.f, 0.f, 0.f, 0.f};
#pragma unroll
  for (int m = 0; m < 4; ++m)
#pragma unroll
    for (int n = 0; n < 4; ++n) acc[m][n] = fzero;

  stage(0, 0);
  __syncthreads();

  int buf = 0;
  for (int t = 0; t < NT; ++t) {
    if (t + 1 < NT) stage(buf ^ 1, t + 1);
    bf16x8 af[4], bf[4];
#pragma unroll
    for (int m = 0; m < 4; ++m) {
      int row = wm * 64 + m * 16 + (lane & 15);
      af[m] = *(const bf16x8*)&AL[buf][row * 32 + (((lane >> 4) ^ ((row >> 1) & 3)) << 3)];
    }
#pragma unroll
    for (int n = 0; n < 4; ++n) {
      int row = wn * 64 + n * 16 + (lane & 15);
      bf[n] = *(const bf16x8*)&BL[buf][row * 32 + (((lane >> 4) ^ ((row >> 1) & 3)) << 3)];
    }
    __builtin_amdgcn_s_setprio(1);
#pragma unroll
    for (int m = 0; m < 4; ++m)
#pragma unroll
      for (int n = 0; n < 4; ++n)
        acc[m][n] = __builtin_amdgcn_mfma_f32_16x16x32_bf16(af[m], bf[n], acc[m][n], 0, 0, 0);
    __builtin_amdgcn_s_setprio(0);
    __syncthreads();
    buf ^= 1;
  }

  float bv[4];
#pragma unroll
  for (int n = 0; n < 4; ++n)
    bv[n] = bias[(size_t)e * NTOT + n0 + wn * 64 + n * 16 + (lane & 15)];

#pragma unroll
  for (int m = 0; m < 4; ++m) {
    int rbase = p0 + wm * 64 + m * 16 + ((lane >> 4) << 2);
#pragma unroll
    for (int n = 0; n < 4; ++n) {
      int col = n0 + wn * 64 + n * 16 + (lane & 15);
#pragma unroll
      for (int r = 0; r < 4; ++r) {
        int rowp = rbase + r;
        if (rowp < off_e1) {
          float v = acc[m][n][r] + bv[n];
          if constexpr (MODE == 0) v = gelu_fast(v);
          outp[(size_t)rowp * NTOT + col] = f2bf(v);
        }
      }
    }
  }
}

// ---------------- combine (layer 0): xh = bf16(w0*yb[s0] + w1*yb[s1]) ----------------
__global__ __launch_bounds__(256) void combine0_kernel(const u16* __restrict__ yb,
    const int* __restrict__ topk_idx, const float* __restrict__ topk_w,
    u16* __restrict__ xh)
{
  int t = blockIdx.x;
  int d = threadIdx.x * 4;
  int s0 = topk_idx[t*2] >> 3, s1 = topk_idx[t*2 + 1] >> 3;
  float w0 = topk_w[t*2], w1 = topk_w[t*2 + 1];
  u16x4 y0 = *(const u16x4*)(yb + (size_t)s0 * DM + d);
  u16x4 y1 = *(const u16x4*)(yb + (size_t)s1 * DM + d);
  u16x4 hv;
#pragma unroll
  for (int j = 0; j < 4; ++j)
    hv[j] = f2bf(bf2f(y0[j]) * w0 + bf2f(y1[j]) * w1);
  *(u16x4*)(xh + (size_t)t * DM + d) = hv;
}

// ---------------- combine (layer 1) + LayerNorm ----------------
__global__ __launch_bounds__(256) void combine1_ln_kernel(const u16* __restrict__ yb,
    const int* __restrict__ topk_idx, const float* __restrict__ topk_w,
    const float* __restrict__ g, const float* __restrict__ b, float* __restrict__ out)
{
  int t = blockIdx.x;
  int d = threadIdx.x * 4;
  int s0 = topk_idx[t*2] >> 3, s1 = topk_idx[t*2 + 1] >> 3;
  float w0 = topk_w[t*2], w1 = topk_w[t*2 + 1];
  u16x4 y0 = *(const u16x4*)(yb + (size_t)s0 * DM + d);
  u16x4 y1 = *(const u16x4*)(yb + (size_t)s1 * DM + d);
  f32x4 v;
#pragma unroll
  for (int j = 0; j < 4; ++j)
    v[j] = bf2f(y0[j]) * w0 + bf2f(y1[j]) * w1;
  float s = v.x + v.y + v.z + v.w;
  float sq = v.x*v.x + v.y*v.y + v.z*v.z + v.w*v.w;
#pragma unroll
  for (int sh = 32; sh; sh >>= 1) { s += __shfl_xor(s, sh); sq += __shfl_xor(sq, sh); }
  __shared__ float red[8];
  int wave = threadIdx.x >> 6, lane = threadIdx.x & 63;
  if (lane == 0) { red[wave] = s; red[4 + wave] = sq; }
  __syncthreads();
  s = red[0] + red[1] + red[2] + red[3];
  sq = red[4] + red[5] + red[6] + red[7];
  float mu = s * (1.0f / DM);
  float var = sq * (1.0f / DM) - mu * mu;
  float inv = rsqrtf(var + LN_EPS);
  f32x4 gv = *(const f32x4*)(g + d);
  f32x4 bv = *(const f32x4*)(b + d);
  f32x4 o;
  o.x = (v.x - mu) * inv * gv.x + bv.x;
  o.y = (v.y - mu) * inv * gv.y + bv.y;
  o.z = (v.z - mu) * inv * gv.z + bv.z;
  o.w = (v.w - mu) * inv * gv.w + bv.w;
  *(f32x4*)(out + (size_t)t * DM + d) = o;
}

extern "C" void kernel_launch(void* const* d_in, const int* in_sizes, int n_in,
                              void* d_out, int out_size, void* d_ws, size_t ws_size,
                              hipStream_t stream)
{
  const int*   tokens = (const int*)d_in[0];
  const float* sym    = (const float*)d_in[1];
  const float* emb    = (const float*)d_in[2];
  const float* gate_w = (const float*)d_in[3];
  const float* gate_b = (const float*)d_in[4];
  const float* w1     = (const float*)d_in[5];
  const float* b1     = (const float*)d_in[6];
  const float* w2     = (const float*)d_in[7];
  const float* b2     = (const float*)d_in[8];
  const float* ln_g   = (const float*)d_in[9];
  const float* ln_b   = (const float*)d_in[10];

  char* ws = (char*)d_ws;
  u16*   yb  = (u16*)  (ws);                     //  33.5MB [16384][1024] bf16 y
  u16*   xh  = (u16*)  (ws + 33554432);          //  16MB
  u16*   xl  = (u16*)  (ws + 50331648);          //  16MB
  u16*   hh  = (u16*)  (ws + 67108864);          // 128MB [16384][4096] bf16
  float* W2G   = (float*)(ws + 201326592);       //   1MB [8][4096][8]
  float* Rpart = (float*)(ws + 202375168);       //  16MB [16][16384][8]
  float* B2G   = (float*)(ws + 219152384);       //  256B
  float* R     = (float*)(ws + 219152640);       // 512KB [16384][8]
  u16*   wTh = (u16*)  (ws + 335544320);         //  64MB
  u16*   wTl = (u16*)  (ws + 402653184);         //  64MB (L0-GEMM1 only)
  int*   pair_token = (int*)  (ws + 469762048);  //  64KB
  int*   topk_idx   = (int*)  (ws + 469893120);  //  64KB (expert | slot<<3)
  float* topk_w     = (float*)(ws + 469958656);  //  64KB
  int*   meta       = (int*)  (ws + 470024192);  //  3KB

  // ================= layer 0 =================
  embed_gate_kernel<<<T_TOK, 256, 0, stream>>>(tokens, sym, emb, gate_w, gate_b,
                                               xh, xl, topk_idx, topk_w);
  count_kernel<<<T_TOK / 256, 256, 0, stream>>>(topk_idx, meta);
  scan_kernel<<<1, 64, 0, stream>>>(meta);
  scatter_kernel<<<T_TOK / 256, 256, 0, stream>>>(topk_idx, meta, pair_token);

  w2g_kernel<<<NE * DFF / 4, 256, 0, stream>>>(w2, gate_w + (size_t)DM * NE, W2G);
  b2g_kernel<<<16, 256, 0, stream>>>(b2, gate_w + (size_t)DM * NE, B2G);

  transpose_kernel<true><<<dim3(DFF / 64, DM / 64, NE), 256, 0, stream>>>(
      w1, wTh, wTl, DM, DFF);
  gemm256_kernel<DM, 3, DFF, true><<<dim3(DFF / 256, MT256), 512, 0, stream>>>(
      xh, xl, wTh, wTl, b1, meta + 8, meta + 32, pair_token, hh, W2G, Rpart);

  reducer_kernel<<<NPAIR * 8 / 256, 256, 0, stream>>>(Rpart, R);

  transpose_kernel<false><<<dim3(DM / 64, DFF / 64, NE), 256, 0, stream>>>(
      w2, wTh, nullptr, DFF, DM);
  gemm128_kernel<DFF, DM, false, 2><<<dim3(DM / 128, MT128), 256, 0, stream>>>(
      hh, wTh, b2, meta + 8, meta + 104, pair_token, yb);

  combine0_kernel<<<T_TOK, 256, 0, stream>>>(yb, topk_idx, topk_w, xh);

  // ================= layer 1 =================
  gate1_kernel<<<T_TOK / 256, 256, 0, stream>>>(R, B2G, gate_b + NE,
                                                topk_idx, topk_w);
  count_kernel<<<T_TOK / 256, 256, 0, stream>>>(topk_idx, meta);
  scan_kernel<<<1, 64, 0, stream>>>(meta);
  scatter_kernel<<<T_TOK / 256, 256, 0, stream>>>(topk_idx, meta, pair_token);

  transpose_kernel<false><<<dim3(DFF / 64, DM / 64, NE), 256, 0, stream>>>(
      w1 + (size_t)NE * DM * DFF, wTh, nullptr, DM, DFF);
  gemm128_kernel<DM, DFF, true, 0><<<dim3(DFF / 128, MT128), 256, 0, stream>>>(
      xh, wTh, b1 + (size_t)NE * DFF, meta + 8, meta + 104, pair_token, hh);

  transpose_kernel<false><<<dim3(DM / 64, DFF / 64, NE), 256, 0, stream>>>(
      w2 + (size_t)NE * DFF * DM, wTh, nullptr, DFF, DM);
  gemm128_kernel<DFF, DM, false, 2><<<dim3(DM / 128, MT128), 256, 0, stream>>>(
      hh, wTh, b2 + (size_t)NE * DM, meta + 8, meta + 104, pair_token, yb);

  combine1_ln_kernel<<<T_TOK, 256, 0, stream>>>(yb, topk_idx, topk_w,
                                                ln_g, ln_b, (float*)d_out);
}

// Round 14
// 1538.686 us; speedup vs baseline: 1.2395x; 1.0259x over previous
//
#include <hip/hip_runtime.h>
#include <math.h>

#define T_TOK 8192
#define DM 1024
#define DFF 4096
#define NE 8
#define NPAIR 16384
#define MT256 72
#define MT128 136
#define LN_EPS 1e-5f

typedef __attribute__((ext_vector_type(8))) short bf16x8;
typedef __attribute__((ext_vector_type(4))) float f32x4;
typedef __attribute__((ext_vector_type(4))) unsigned short u16x4;
typedef __attribute__((ext_vector_type(8))) unsigned short u16x8;
typedef unsigned int u32;
typedef unsigned short u16;

__device__ __forceinline__ u16 f2bf(float f) {
  union { float f; u32 u; } v; v.f = f;
  u32 r = (v.u + 0x7fffu + ((v.u >> 16) & 1u)) >> 16;
  return (u16)r;
}
__device__ __forceinline__ float bf2f(u16 h) {
  union { u32 u; float f; } v; v.u = ((u32)h) << 16; return v.f;
}
__device__ __forceinline__ float gelu_exact(float v) {
  return 0.5f * v * (1.0f + erff(v * 0.70710678118654752f));
}
__device__ __forceinline__ float gelu_fast(float v) {
  float u = v * (0.7978845608f + 0.0356774081f * v * v);
  float t = __expf(-2.0f * fabsf(u));
  float th = (1.0f - t) / (1.0f + t);
  th = copysignf(th, u);
  return 0.5f * v * (1.0f + th);
}

__device__ __forceinline__ void gll16(const void* g, void* l) {
  __builtin_amdgcn_global_load_lds(
      (const __attribute__((address_space(1))) u32*)g,
      (__attribute__((address_space(3))) u32*)l, 16, 0, 0);
}

// XCD-grouped work remap: all ntiles of one work-mtile share an XCD class.
// Requires gridDim.x%8==0 and gridDim.y%8==0 (else identity). Bijective.
__device__ __forceinline__ void xcd_remap(int& M, int& nt) {
  if (((gridDim.x & 7) == 0) && ((gridDim.y & 7) == 0)) {
    int c = blockIdx.x & 7, q = blockIdx.x >> 3;
    M  = ((blockIdx.y >> 3) << 3) + c;
    nt = (q << 3) + (blockIdx.y & 7);
  } else {
    M = blockIdx.y; nt = blockIdx.x;
  }
}

// -------- fused embed + layer-0 gate --------
__global__ __launch_bounds__(256) void embed_gate_kernel(const int* __restrict__ tok,
    const float* __restrict__ sym, const float* __restrict__ emb,
    const float* __restrict__ gw, const float* __restrict__ gb,
    u16* __restrict__ xh, u16* __restrict__ xl,
    int* __restrict__ topk_idx, float* __restrict__ topk_w)
{
  int t = blockIdx.x;
  int b = t >> 11;
  int tk = tok[t];
  int d = threadIdx.x * 4;
  f32x4 e = *(const f32x4*)(emb + (size_t)tk * DM + d);
  f32x4 s = *(const f32x4*)(sym + (size_t)b * DM + d);
  f32x4 v = e + s;
  u16x4 hv, lv;
#pragma unroll
  for (int j = 0; j < 4; ++j) {
    u16 hb = f2bf(v[j]);
    hv[j] = hb;
    lv[j] = f2bf(v[j] - bf2f(hb));
  }
  *(u16x4*)(xh + (size_t)t * DM + d) = hv;
  *(u16x4*)(xl + (size_t)t * DM + d) = lv;

  double a[8] = {0,0,0,0,0,0,0,0};
#pragma unroll
  for (int q = 0; q < 4; ++q) {
    const f32x4* gr = (const f32x4*)(gw + (size_t)(d + q) * 8);
    f32x4 g0 = gr[0], g1 = gr[1];
    double xv = (double)v[q];
    a[0] += xv*(double)g0.x; a[1] += xv*(double)g0.y;
    a[2] += xv*(double)g0.z; a[3] += xv*(double)g0.w;
    a[4] += xv*(double)g1.x; a[5] += xv*(double)g1.y;
    a[6] += xv*(double)g1.z; a[7] += xv*(double)g1.w;
  }
#pragma unroll
  for (int j = 0; j < 8; ++j) {
#pragma unroll
    for (int sh = 32; sh; sh >>= 1) a[j] += __shfl_xor(a[j], sh);
  }
  __shared__ double red[4][8];
  int wave = threadIdx.x >> 6, lane = threadIdx.x & 63;
  if (lane == 0) {
#pragma unroll
    for (int j = 0; j < 8; ++j) red[wave][j] = a[j];
  }
  __syncthreads();
  if (threadIdx.x == 0) {
    double lg[8];
#pragma unroll
    for (int j = 0; j < 8; ++j)
      lg[j] = red[0][j] + red[1][j] + red[2][j] + red[3][j] + (double)gb[j];
    double m = lg[0];
    for (int j = 1; j < 8; ++j) m = lg[j] > m ? lg[j] : m;
    double p[8], sum = 0.0;
    for (int j = 0; j < 8; ++j) { p[j] = exp(lg[j] - m); sum += p[j]; }
    for (int j = 0; j < 8; ++j) p[j] /= sum;
    int j0 = 0; double b0 = p[0];
    for (int j = 1; j < 8; ++j) if (p[j] > b0) { b0 = p[j]; j0 = j; }
    int j1 = (j0 == 0) ? 1 : 0; double b1v = p[j1];
    for (int j = 0; j < 8; ++j) if (j != j0 && p[j] > b1v) { b1v = p[j]; j1 = j; }
    topk_idx[t*2]   = j0; topk_idx[t*2+1] = j1;
    topk_w[t*2]     = (float)b0; topk_w[t*2+1] = (float)b1v;
  }
}

// meta: [0..7]=totals, [8..16]=offsets, [32..103]=tiletab256, [104..239]=tiletab128,
//       [256..511]=blockcnt[32][8], [512..767]=blockbase[32][8]
__global__ __launch_bounds__(256) void count_kernel(const int* __restrict__ topk_idx,
    int* __restrict__ meta)
{
  __shared__ int hist[8];
  int tid = threadIdx.x;
  if (tid < 8) hist[tid] = 0;
  __syncthreads();
  int t = blockIdx.x * 256 + tid;
  atomicAdd(&hist[topk_idx[t*2] & 7], 1);
  atomicAdd(&hist[topk_idx[t*2+1] & 7], 1);
  __syncthreads();
  if (tid < 8) meta[256 + blockIdx.x * 8 + tid] = hist[tid];
}

__global__ __launch_bounds__(64) void scan_kernel(int* __restrict__ meta)
{
  __shared__ int tot[8], off[9], tb2[8], tb1[8];
  int lane = threadIdx.x;
  if (lane < 8) {
    int s = 0;
    for (int b = 0; b < 32; ++b) s += meta[256 + b * 8 + lane];
    tot[lane] = s;
  }
  __syncthreads();
  if (lane == 0) {
    int s = 0, n2 = 0, n1 = 0;
    for (int e = 0; e < 8; ++e) {
      off[e] = s; s += tot[e];
      tb2[e] = n2; n2 += (tot[e] + 255) >> 8;
      tb1[e] = n1; n1 += (tot[e] + 127) >> 7;
    }
    off[8] = s;
    for (int i = n2; i < MT256; ++i) meta[32 + i] = -1;
    for (int i = n1; i < MT128; ++i) meta[104 + i] = -1;
  }
  __syncthreads();
  if (lane < 9) meta[8 + lane] = off[lane];
  if (lane < 8) {
    meta[lane] = tot[lane];
    int n2 = (tot[lane] + 255) >> 8;
    for (int i = 0; i < n2; ++i) meta[32 + tb2[lane] + i] = (lane << 16) | i;
    int n1 = (tot[lane] + 127) >> 7;
    for (int i = 0; i < n1; ++i) meta[104 + tb1[lane] + i] = (lane << 16) | i;
    int run = off[lane];
    for (int b = 0; b < 32; ++b) {
      meta[512 + b * 8 + lane] = run;
      run += meta[256 + b * 8 + lane];
    }
  }
}

__global__ __launch_bounds__(256) void scatter_kernel(int* __restrict__ topk_idx,
    const int* __restrict__ meta, int* __restrict__ pair_token)
{
  __shared__ int hist[8];
  __shared__ int base[8];
  int tid = threadIdx.x;
  if (tid < 8) { hist[tid] = 0; base[tid] = meta[512 + blockIdx.x * 8 + tid]; }
  __syncthreads();
  int t = blockIdx.x * 256 + tid;
#pragma unroll
  for (int k = 0; k < 2; ++k) {
    int e = topk_idx[t*2 + k] & 7;
    int pos = atomicAdd(&hist[e], 1);
    int slot = base[e] + pos;
    pair_token[slot] = t;
    topk_idx[t*2 + k] = e | (slot << 3);
  }
}

// ------------- weight transpose+split: f32 [K][N] -> bf16 hi/lo [N][K] -------------
template<bool LO>
__global__ __launch_bounds__(256) void transpose_kernel(const float* __restrict__ src,
    u16* __restrict__ dsth, u16* __restrict__ dstl, int K, int N)
{
  __shared__ float tile[64][65];
  int e = blockIdx.z;
  const float* s = src + (size_t)e * K * N;
  size_t dbase = (size_t)e * K * N;
  int n0 = blockIdx.x * 64, k0 = blockIdx.y * 64;
  int tid = threadIdx.x;
#pragma unroll
  for (int j = 0; j < 4; ++j) {
    int kl = j * 16 + (tid >> 4);
    int nn = (tid & 15) * 4;
    f32x4 v = *(const f32x4*)(s + (size_t)(k0 + kl) * N + n0 + nn);
    tile[nn + 0][kl] = v.x;
    tile[nn + 1][kl] = v.y;
    tile[nn + 2][kl] = v.z;
    tile[nn + 3][kl] = v.w;
  }
  __syncthreads();
#pragma unroll
  for (int it = 0; it < 2; ++it) {
    int task = it * 256 + tid;
    int nr = task >> 3;
    int ch = task & 7;
    u16x8 oh, ol;
#pragma unroll
    for (int j = 0; j < 8; ++j) {
      float v = tile[nr][ch*8 + j];
      u16 hb = f2bf(v);
      oh[j] = hb;
      if (LO) ol[j] = f2bf(v - bf2f(hb));
    }
    size_t doff = dbase + (size_t)(n0 + nr) * K + k0 + ch*8;
    *(u16x8*)(dsth + doff) = oh;
    if (LO) *(u16x8*)(dstl + doff) = ol;
  }
}

// ---- W2G[e] = w2[e] @ gw1  ([E][DFF][8], f32) ----
__global__ __launch_bounds__(256) void w2g_kernel(const float* __restrict__ w2,
    const float* __restrict__ gw, float* __restrict__ w2g)
{
  int wid = blockIdx.x * 4 + (threadIdx.x >> 6);
  int lane = threadIdx.x & 63;
  int e = wid >> 12, f = wid & 4095;
  const float* row = w2 + ((size_t)e * DFF + f) * DM;
  float a0=0,a1=0,a2=0,a3=0,a4=0,a5=0,a6=0,a7=0;
  for (int i = 0; i < 4; ++i) {
    int d0 = i * 256 + lane * 4;
    f32x4 xv = *(const f32x4*)(row + d0);
#pragma unroll
    for (int q = 0; q < 4; ++q) {
      const f32x4* gr = (const f32x4*)(gw + (size_t)(d0 + q) * 8);
      f32x4 g0 = gr[0], g1 = gr[1];
      float xq = xv[q];
      a0 += xq*g0.x; a1 += xq*g0.y; a2 += xq*g0.z; a3 += xq*g0.w;
      a4 += xq*g1.x; a5 += xq*g1.y; a6 += xq*g1.z; a7 += xq*g1.w;
    }
  }
  float acc[8] = {a0,a1,a2,a3,a4,a5,a6,a7};
#pragma unroll
  for (int j = 0; j < 8; ++j) {
#pragma unroll
    for (int sh = 32; sh; sh >>= 1) acc[j] += __shfl_xor(acc[j], sh);
  }
  if (lane == 0) {
#pragma unroll
    for (int j = 0; j < 8; ++j) w2g[(size_t)wid * 8 + j] = acc[j];
  }
}

__global__ __launch_bounds__(256) void b2g_kernel(const float* __restrict__ b2,
    const float* __restrict__ gw, float* __restrict__ b2g)
{
  int w = blockIdx.x * 4 + (threadIdx.x >> 6);
  int lane = threadIdx.x & 63;
  int e = w >> 3, j = w & 7;
  float acc = 0.f;
  for (int i = 0; i < 16; ++i) {
    int d = i * 64 + lane;
    acc += b2[(size_t)e * DM + d] * gw[(size_t)d * 8 + j];
  }
#pragma unroll
  for (int sh = 32; sh; sh >>= 1) acc += __shfl_xor(acc, sh);
  if (lane == 0) b2g[w] = acc;
}

// ---- layer-1 gate: sums Rpart partials inline (fixed order, deterministic) ----
__global__ __launch_bounds__(256) void gate1_kernel(const float* __restrict__ Rpart,
    const float* __restrict__ b2g, const float* __restrict__ gb,
    int* __restrict__ topk_idx, float* __restrict__ topk_w)
{
  int t = blockIdx.x * 256 + threadIdx.x;
  int v0 = topk_idx[t*2], v1 = topk_idx[t*2+1];
  int e0 = v0 & 7, e1 = v1 & 7;
  int s0 = v0 >> 3, s1 = v1 >> 3;
  float r0[8] = {0,0,0,0,0,0,0,0}, r1[8] = {0,0,0,0,0,0,0,0};
  for (int nt = 0; nt < 16; ++nt) {
    const float* p0r = Rpart + ((size_t)nt * NPAIR + s0) * 8;
    const float* p1r = Rpart + ((size_t)nt * NPAIR + s1) * 8;
#pragma unroll
    for (int j = 0; j < 8; ++j) { r0[j] += p0r[j]; r1[j] += p1r[j]; }
  }
  double w0 = (double)topk_w[t*2], w1 = (double)topk_w[t*2+1];
  double a[8];
#pragma unroll
  for (int j = 0; j < 8; ++j)
    a[j] = w0 * ((double)r0[j] + (double)b2g[e0*8+j])
         + w1 * ((double)r1[j] + (double)b2g[e1*8+j])
         + (double)gb[j];
  double m = a[0];
  for (int j = 1; j < 8; ++j) m = a[j] > m ? a[j] : m;
  double p[8], sum = 0.0;
  for (int j = 0; j < 8; ++j) { p[j] = exp(a[j] - m); sum += p[j]; }
  for (int j = 0; j < 8; ++j) p[j] /= sum;
  int j0 = 0; double b0 = p[0];
  for (int j = 1; j < 8; ++j) if (p[j] > b0) { b0 = p[j]; j0 = j; }
  int j1 = (j0 == 0) ? 1 : 0; double b1v = p[j1];
  for (int j = 0; j < 8; ++j) if (j != j0 && p[j] > b1v) { b1v = p[j]; j1 = j; }
  topk_idx[t*2]   = j0; topk_idx[t*2+1] = j1;
  topk_w[t*2]     = (float)b0; topk_w[t*2+1] = (float)b1v;
}

// ====== 256x256 grouped GEMM, BK=64, 8-phase, counted vmcnt ======
// outh = bf16(gelu_exact) + fused R-partials via W2G  [L0-GEMM1]
template<int K0, int NSEG, int NTOT, bool GATHER>
__global__ __launch_bounds__(512, 2) void gemm256_kernel(
    const u16* __restrict__ Ah, const u16* __restrict__ Al,
    const u16* __restrict__ Bh, const u16* __restrict__ Bl,
    const float* __restrict__ bias, const int* __restrict__ off,
    const int* __restrict__ tiletab, const int* __restrict__ pair_token,
    u16* __restrict__ outh, const float* __restrict__ W2G,
    float* __restrict__ Rpart)
{
  constexpr int NT = (K0 * NSEG) / 64;
  static_assert(NT >= 2, "");
  int Mi, nti;
  xcd_remap(Mi, nti);
  const int tt = tiletab[Mi];
  if (tt < 0) return;
  const int e  = tt >> 16;
  const int mt = tt & 0xffff;
  const int off_e = off[e], off_e1 = off[e + 1];
  const int p0 = off_e + mt * 256;
  const int n0 = nti * 256;

  __shared__ __align__(16) u16 ALs[2][2][8192];
  __shared__ __align__(16) u16 BLs[2][2][8192];

  const int tid  = threadIdx.x;
  const int lane = tid & 63;
  const int wave = tid >> 6;
  const int wm = wave >> 2;
  const int wn = wave & 3;
  const int wbase = tid & 448;

  size_t aoff[2], boff[2];
#pragma unroll
  for (int i = 0; i < 2; ++i) {
    int c = i * 512 + tid;
    int r = c >> 2;
    int cs = (c & 3) ^ ((r >> 1) & 3);
    int idx = p0 + r;
    if (idx >= off_e1) idx = p0;
    int ar = GATHER ? pair_token[idx] : idx;
    aoff[i] = (size_t)ar * K0 + (size_t)(cs * 8);
    boff[i] = ((size_t)e * NTOT + n0 + r) * K0 + (size_t)(cs * 8);
  }

  auto stageA = [&](int t, int kh) {
    int kk = t * 64 + kh * 32;
    int seg = (NSEG == 3) ? (kk >> 10) : 0;
    int kc  = (NSEG == 3) ? (kk & (K0 - 1)) : kk;
    const u16* base = (NSEG == 3 && seg == 1) ? Al : Ah;
    u16* dst = &ALs[t & 1][kh][0];
#pragma unroll
    for (int i = 0; i < 2; ++i)
      gll16(base + aoff[i] + kc, dst + (i * 512 + wbase) * 8);
  };
  auto stageB = [&](int t, int kh) {
    int kk = t * 64 + kh * 32;
    int seg = (NSEG == 3) ? (kk >> 10) : 0;
    int kc  = (NSEG == 3) ? (kk & (K0 - 1)) : kk;
    const u16* base = (NSEG == 3 && seg == 2) ? Bl : Bh;
    u16* dst = &BLs[t & 1][kh][0];
#pragma unroll
    for (int i = 0; i < 2; ++i)
      gll16(base + boff[i] + kc, dst + (i * 512 + wbase) * 8);
  };

  f32x4 acc[8][4];
  const f32x4 fzero = {0.f, 0.f, 0.f, 0.f};
#pragma unroll
  for (int m = 0; m < 8; ++m)
#pragma unroll
    for (int n = 0; n < 4; ++n) acc[m][n] = fzero;

  auto rdA4 = [&](bf16x8* dst, int par, int kh, int mbase) {
    const u16* L = &ALs[par][kh][0];
#pragma unroll
    for (int mf = 0; mf < 4; ++mf) {
      int row = wm * 128 + (mbase + mf) * 16 + (lane & 15);
      dst[mf] = *(const bf16x8*)&L[row * 32 + (((lane >> 4) ^ ((row >> 1) & 3)) << 3)];
    }
  };
  auto rdB4 = [&](bf16x8* dst, int par, int kh) {
    const u16* L = &BLs[par][kh][0];
#pragma unroll
    for (int nf = 0; nf < 4; ++nf) {
      int row = wn * 64 + nf * 16 + (lane & 15);
      dst[nf] = *(const bf16x8*)&L[row * 32 + (((lane >> 4) ^ ((row >> 1) & 3)) << 3)];
    }
  };

#define MMBLK(MB, A4, B4)                                                        \
  {                                                                              \
    __builtin_amdgcn_s_setprio(1);                                               \
    _Pragma("unroll")                                                            \
    for (int mf = 0; mf < 4; ++mf)                                               \
      _Pragma("unroll")                                                          \
      for (int nf = 0; nf < 4; ++nf)                                             \
        acc[(MB) + mf][nf] = __builtin_amdgcn_mfma_f32_16x16x32_bf16(            \
            (A4)[mf], (B4)[nf], acc[(MB) + mf][nf], 0, 0, 0);                    \
    __builtin_amdgcn_s_setprio(0);                                               \
  }

  stageA(0, 0); stageB(0, 0);
  stageA(0, 1); stageB(0, 1);
  stageA(1, 0); stageB(1, 0);
  asm volatile("s_waitcnt vmcnt(8)" ::: "memory");
  __builtin_amdgcn_s_barrier();
  asm volatile("" ::: "memory");

  for (int t = 0; t < NT; ++t) {
    const int par = t & 1;
    bf16x8 bA[4], aA[4], aB[4], bC[4], aC[4], aD[4];
    rdB4(bA, par, 0);
    rdA4(aA, par, 0, 0);
    if (t + 1 < NT) stageA(t + 1, 1);
    __builtin_amdgcn_s_barrier();
    MMBLK(0, aA, bA);
    __builtin_amdgcn_s_barrier();
    rdA4(aB, par, 0, 4);
    if (t + 1 < NT) stageB(t + 1, 1);
    __builtin_amdgcn_s_barrier();
    MMBLK(4, aB, bA);
    if (t + 1 < NT) { asm volatile("s_waitcnt vmcnt(8)" ::: "memory"); }
    else            { asm volatile("s_waitcnt vmcnt(0)" ::: "memory"); }
    __builtin_amdgcn_s_barrier();
    asm volatile("" ::: "memory");
    rdB4(bC, par, 1);
    rdA4(aC, par, 1, 0);
    if (t + 2 < NT) stageA(t + 2, 0);
    __builtin_amdgcn_s_barrier();
    MMBLK(0, aC, bC);
    __builtin_amdgcn_s_barrier();
    rdA4(aD, par, 1, 4);
    if (t + 2 < NT) stageB(t + 2, 0);
    __builtin_amdgcn_s_barrier();
    MMBLK(4, aD, bC);
    if (t + 1 < NT) {
      if (t + 2 < NT) { asm volatile("s_waitcnt vmcnt(8)" ::: "memory"); }
      else            { asm volatile("s_waitcnt vmcnt(4)" ::: "memory"); }
      __builtin_amdgcn_s_barrier();
      asm volatile("" ::: "memory");
    }
  }
#undef MMBLK

  float bv[4];
#pragma unroll
  for (int nf = 0; nf < 4; ++nf)
    bv[nf] = bias[(size_t)e * NTOT + n0 + wn * 64 + nf * 16 + (lane & 15)];

  __syncthreads();                       // reclaim LDS for Rpt
  float* Rpt = (float*)&ALs[0][0][0];    // [4 wn][256 rows][8] f32 = 32 KB
  f32x4 wg0[4], wg1[4];
#pragma unroll
  for (int nf = 0; nf < 4; ++nf) {
    int col = n0 + wn * 64 + nf * 16 + (lane & 15);
    const float* wp = W2G + ((size_t)e * NTOT + col) * 8;
    wg0[nf] = *(const f32x4*)wp;
    wg1[nf] = *(const f32x4*)(wp + 4);
  }
#pragma unroll
  for (int mf = 0; mf < 8; ++mf) {
    f32x4 pr0[4], pr1[4];
#pragma unroll
    for (int r = 0; r < 4; ++r) { pr0[r] = fzero; pr1[r] = fzero; }
    int rbase = p0 + wm * 128 + mf * 16 + ((lane >> 4) << 2);
#pragma unroll
    for (int nf = 0; nf < 4; ++nf) {
      int col = n0 + wn * 64 + nf * 16 + (lane & 15);
#pragma unroll
      for (int r = 0; r < 4; ++r) {
        float v = gelu_exact(acc[mf][nf][r] + bv[nf]);
        if (rbase + r < off_e1)
          outh[(size_t)(rbase + r) * NTOT + col] = f2bf(v);
        pr0[r] += v * wg0[nf];
        pr1[r] += v * wg1[nf];
      }
    }
#pragma unroll
    for (int r = 0; r < 4; ++r) {
#pragma unroll
      for (int sh = 1; sh < 16; sh <<= 1) {
#pragma unroll
        for (int q = 0; q < 4; ++q) {
          pr0[r][q] += __shfl_xor(pr0[r][q], sh);
          pr1[r][q] += __shfl_xor(pr1[r][q], sh);
        }
      }
      if ((lane & 15) == 0) {
        int rl = wm * 128 + mf * 16 + ((lane >> 4) << 2) + r;
        float* dst = Rpt + ((size_t)(wn * 256 + rl)) * 8;
        *(f32x4*)dst = pr0[r];
        *(f32x4*)(dst + 4) = pr1[r];
      }
    }
  }
  __syncthreads();
  for (int i = tid; i < 256 * 8; i += 512) {
    int rl = i >> 3, j = i & 7;
    float ssum = Rpt[(size_t)(0 * 256 + rl) * 8 + j]
               + Rpt[(size_t)(1 * 256 + rl) * 8 + j]
               + Rpt[(size_t)(2 * 256 + rl) * 8 + j]
               + Rpt[(size_t)(3 * 256 + rl) * 8 + j];
    int p = p0 + rl;
    if (p < off_e1)
      Rpart[((size_t)nti * NPAIR + p) * 8 + j] = ssum;
  }
}

// ====== 128x128 grouped GEMM, BK=32, ring-2, 32KB LDS ======
// MODE 0: outh = bf16(gelu_fast)   [L1-GEMM1]
// MODE 2: outy = bf16(acc + bias)  [GEMM2s -> yb]
template<int K0, int NTOT, bool GATHER, int MODE>
__global__ __launch_bounds__(256, 4) void gemm128_kernel(
    const u16* __restrict__ Ah, const u16* __restrict__ Bh,
    const float* __restrict__ bias, const int* __restrict__ off,
    const int* __restrict__ tiletab, const int* __restrict__ pair_token,
    u16* __restrict__ outp)
{
  constexpr int NT = K0 / 32;
  int Mi, nti;
  xcd_remap(Mi, nti);
  const int tt = tiletab[Mi];
  if (tt < 0) return;
  const int e  = tt >> 16;
  const int mt = tt & 0xffff;
  const int off_e = off[e], off_e1 = off[e + 1];
  const int p0 = off_e + mt * 128;
  const int n0 = nti * 128;

  __shared__ __align__(16) u16 AL[2][4096];
  __shared__ __align__(16) u16 BL[2][4096];

  const int tid  = threadIdx.x;
  const int lane = tid & 63;
  const int wave = tid >> 6;
  const int wm = wave >> 1, wn = wave & 1;
  const int wbase = tid & 192;

  size_t aoff[2], boff[2];
#pragma unroll
  for (int i = 0; i < 2; ++i) {
    int c = i * 256 + tid;
    int r = c >> 2;
    int cs = (c & 3) ^ ((r >> 1) & 3);
    int idx = p0 + r;
    if (idx >= off_e1) idx = p0;
    int ar = GATHER ? pair_token[idx] : idx;
    aoff[i] = (size_t)ar * K0 + (size_t)(cs * 8);
    boff[i] = ((size_t)e * NTOT + n0 + r) * K0 + (size_t)(cs * 8);
  }

  auto stage = [&](int b, int t) {
    int kc = t * 32;
#pragma unroll
    for (int i = 0; i < 2; ++i) {
      int cb = i * 256 + wbase;
      gll16(Ah + aoff[i] + kc, &AL[b][cb * 8]);
      gll16(Bh + boff[i] + kc, &BL[b][cb * 8]);
    }
  };

  f32x4 acc[4][4];
  const f32x4 fzero = {0.f, 0.f, 0.f, 0.f};
#pragma unroll
  for (int m = 0; m < 4; ++m)
#pragma unroll
    for (int n = 0; n < 4; ++n) acc[m][n] = fzero;

  stage(0, 0);
  __syncthreads();

  int buf = 0;
  for (int t = 0; t < NT; ++t) {
    if (t + 1 < NT) stage(buf ^ 1, t + 1);
    bf16x8 af[4], bf[4];
#pragma unroll
    for (int m = 0; m < 4; ++m) {
      int row = wm * 64 + m * 16 + (lane & 15);
      af[m] = *(const bf16x8*)&AL[buf][row * 32 + (((lane >> 4) ^ ((row >> 1) & 3)) << 3)];
    }
#pragma unroll
    for (int n = 0; n < 4; ++n) {
      int row = wn * 64 + n * 16 + (lane & 15);
      bf[n] = *(const bf16x8*)&BL[buf][row * 32 + (((lane >> 4) ^ ((row >> 1) & 3)) << 3)];
    }
    __builtin_amdgcn_s_setprio(1);
#pragma unroll
    for (int m = 0; m < 4; ++m)
#pragma unroll
      for (int n = 0; n < 4; ++n)
        acc[m][n] = __builtin_amdgcn_mfma_f32_16x16x32_bf16(af[m], bf[n], acc[m][n], 0, 0, 0);
    __builtin_amdgcn_s_setprio(0);
    __syncthreads();
    buf ^= 1;
  }

  float bv[4];
#pragma unroll
  for (int n = 0; n < 4; ++n)
    bv[n] = bias[(size_t)e * NTOT + n0 + wn * 64 + n * 16 + (lane & 15)];

#pragma unroll
  for (int m = 0; m < 4; ++m) {
    int rbase = p0 + wm * 64 + m * 16 + ((lane >> 4) << 2);
#pragma unroll
    for (int n = 0; n < 4; ++n) {
      int col = n0 + wn * 64 + n * 16 + (lane & 15);
#pragma unroll
      for (int r = 0; r < 4; ++r) {
        int rowp = rbase + r;
        if (rowp < off_e1) {
          float v = acc[m][n][r] + bv[n];
          if constexpr (MODE == 0) v = gelu_fast(v);
          outp[(size_t)rowp * NTOT + col] = f2bf(v);
        }
      }
    }
  }
}

// ---------------- combine (layer 0): xh = bf16(w0*yb[s0] + w1*yb[s1]) ----------------
__global__ __launch_bounds__(256) void combine0_kernel(const u16* __restrict__ yb,
    const int* __restrict__ topk_idx, const float* __restrict__ topk_w,
    u16* __restrict__ xh)
{
  int t = blockIdx.x;
  int d = threadIdx.x * 4;
  int s0 = topk_idx[t*2] >> 3, s1 = topk_idx[t*2 + 1] >> 3;
  float w0 = topk_w[t*2], w1 = topk_w[t*2 + 1];
  u16x4 y0 = *(const u16x4*)(yb + (size_t)s0 * DM + d);
  u16x4 y1 = *(const u16x4*)(yb + (size_t)s1 * DM + d);
  u16x4 hv;
#pragma unroll
  for (int j = 0; j < 4; ++j)
    hv[j] = f2bf(bf2f(y0[j]) * w0 + bf2f(y1[j]) * w1);
  *(u16x4*)(xh + (size_t)t * DM + d) = hv;
}

// ---------------- combine (layer 1) + LayerNorm ----------------
__global__ __launch_bounds__(256) void combine1_ln_kernel(const u16* __restrict__ yb,
    const int* __restrict__ topk_idx, const float* __restrict__ topk_w,
    const float* __restrict__ g, const float* __restrict__ b, float* __restrict__ out)
{
  int t = blockIdx.x;
  int d = threadIdx.x * 4;
  int s0 = topk_idx[t*2] >> 3, s1 = topk_idx[t*2 + 1] >> 3;
  float w0 = topk_w[t*2], w1 = topk_w[t*2 + 1];
  u16x4 y0 = *(const u16x4*)(yb + (size_t)s0 * DM + d);
  u16x4 y1 = *(const u16x4*)(yb + (size_t)s1 * DM + d);
  f32x4 v;
#pragma unroll
  for (int j = 0; j < 4; ++j)
    v[j] = bf2f(y0[j]) * w0 + bf2f(y1[j]) * w1;
  float s = v.x + v.y + v.z + v.w;
  float sq = v.x*v.x + v.y*v.y + v.z*v.z + v.w*v.w;
#pragma unroll
  for (int sh = 32; sh; sh >>= 1) { s += __shfl_xor(s, sh); sq += __shfl_xor(sq, sh); }
  __shared__ float red[8];
  int wave = threadIdx.x >> 6, lane = threadIdx.x & 63;
  if (lane == 0) { red[wave] = s; red[4 + wave] = sq; }
  __syncthreads();
  s = red[0] + red[1] + red[2] + red[3];
  sq = red[4] + red[5] + red[6] + red[7];
  float mu = s * (1.0f / DM);
  float var = sq * (1.0f / DM) - mu * mu;
  float inv = rsqrtf(var + LN_EPS);
  f32x4 gv = *(const f32x4*)(g + d);
  f32x4 bv = *(const f32x4*)(b + d);
  f32x4 o;
  o.x = (v.x - mu) * inv * gv.x + bv.x;
  o.y = (v.y - mu) * inv * gv.y + bv.y;
  o.z = (v.z - mu) * inv * gv.z + bv.z;
  o.w = (v.w - mu) * inv * gv.w + bv.w;
  *(f32x4*)(out + (size_t)t * DM + d) = o;
}

extern "C" void kernel_launch(void* const* d_in, const int* in_sizes, int n_in,
                              void* d_out, int out_size, void* d_ws, size_t ws_size,
                              hipStream_t stream)
{
  const int*   tokens = (const int*)d_in[0];
  const float* sym    = (const float*)d_in[1];
  const float* emb    = (const float*)d_in[2];
  const float* gate_w = (const float*)d_in[3];
  const float* gate_b = (const float*)d_in[4];
  const float* w1     = (const float*)d_in[5];
  const float* b1     = (const float*)d_in[6];
  const float* w2     = (const float*)d_in[7];
  const float* b2     = (const float*)d_in[8];
  const float* ln_g   = (const float*)d_in[9];
  const float* ln_b   = (const float*)d_in[10];

  char* ws = (char*)d_ws;
  u16*   yb  = (u16*)  (ws);                     //  33.5MB [16384][1024] bf16 y
  u16*   xh  = (u16*)  (ws + 33554432);          //  16MB
  u16*   xl  = (u16*)  (ws + 50331648);          //  16MB
  u16*   hh  = (u16*)  (ws + 67108864);          // 128MB [16384][4096] bf16
  float* W2G   = (float*)(ws + 201326592);       //   1MB [8][4096][8]
  float* Rpart = (float*)(ws + 202375168);       //  16MB [16][16384][8]
  float* B2G   = (float*)(ws + 219152384);       //  256B
  u16*   wTh = (u16*)  (ws + 335544320);         //  64MB
  u16*   wTl = (u16*)  (ws + 402653184);         //  64MB (L0-GEMM1 only)
  int*   pair_token = (int*)  (ws + 469762048);  //  64KB
  int*   topk_idx   = (int*)  (ws + 469893120);  //  64KB (expert | slot<<3)
  float* topk_w     = (float*)(ws + 469958656);  //  64KB
  int*   meta       = (int*)  (ws + 470024192);  //  3KB

  // ================= layer 0 =================
  embed_gate_kernel<<<T_TOK, 256, 0, stream>>>(tokens, sym, emb, gate_w, gate_b,
                                               xh, xl, topk_idx, topk_w);
  count_kernel<<<T_TOK / 256, 256, 0, stream>>>(topk_idx, meta);
  scan_kernel<<<1, 64, 0, stream>>>(meta);
  scatter_kernel<<<T_TOK / 256, 256, 0, stream>>>(topk_idx, meta, pair_token);

  w2g_kernel<<<NE * DFF / 4, 256, 0, stream>>>(w2, gate_w + (size_t)DM * NE, W2G);
  b2g_kernel<<<16, 256, 0, stream>>>(b2, gate_w + (size_t)DM * NE, B2G);

  transpose_kernel<true><<<dim3(DFF / 64, DM / 64, NE), 256, 0, stream>>>(
      w1, wTh, wTl, DM, DFF);
  gemm256_kernel<DM, 3, DFF, true><<<dim3(DFF / 256, MT256), 512, 0, stream>>>(
      xh, xl, wTh, wTl, b1, meta + 8, meta + 32, pair_token, hh, W2G, Rpart);

  transpose_kernel<false><<<dim3(DM / 64, DFF / 64, NE), 256, 0, stream>>>(
      w2, wTh, nullptr, DFF, DM);
  gemm128_kernel<DFF, DM, false, 2><<<dim3(DM / 128, MT128), 256, 0, stream>>>(
      hh, wTh, b2, meta + 8, meta + 104, pair_token, yb);

  combine0_kernel<<<T_TOK, 256, 0, stream>>>(yb, topk_idx, topk_w, xh);

  // ================= layer 1 =================
  gate1_kernel<<<T_TOK / 256, 256, 0, stream>>>(Rpart, B2G, gate_b + NE,
                                                topk_idx, topk_w);
  count_kernel<<<T_TOK / 256, 256, 0, stream>>>(topk_idx, meta);
  scan_kernel<<<1, 64, 0, stream>>>(meta);
  scatter_kernel<<<T_TOK / 256, 256, 0, stream>>>(topk_idx, meta, pair_token);

  transpose_kernel<false><<<dim3(DFF / 64, DM / 64, NE), 256, 0, stream>>>(
      w1 + (size_t)NE * DM * DFF, wTh, nullptr, DM, DFF);
  gemm128_kernel<DM, DFF, true, 0><<<dim3(DFF / 128, MT128), 256, 0, stream>>>(
      xh, wTh, b1 + (size_t)NE * DFF, meta + 8, meta + 104, pair_token, hh);

  transpose_kernel<false><<<dim3(DM / 64, DFF / 64, NE), 256, 0, stream>>>(
      w2 + (size_t)NE * DFF * DM, wTh, nullptr, DFF, DM);
  gemm128_kernel<DFF, DM, false, 2><<<dim3(DM / 128, MT128), 256, 0, stream>>>(
      hh, wTh, b2 + (size_t)NE * DM, meta + 8, meta + 104, pair_token, yb);

  combine1_ln_kernel<<<T_TOK, 256, 0, stream>>>(yb, topk_idx, topk_w,
                                                ln_g, ln_b, (float*)d_out);
}

// Round 15
// 1499.804 us; speedup vs baseline: 1.2716x; 1.0259x over previous
//
#include <hip/hip_runtime.h>
#include <math.h>

#define T_TOK 8192
#define DM 1024
#define DFF 4096
#define NE 8
#define NPAIR 16384
#define MT256 72
#define MT128 136
#define LN_EPS 1e-5f

typedef __attribute__((ext_vector_type(8))) short bf16x8;
typedef __attribute__((ext_vector_type(4))) float f32x4;
typedef __attribute__((ext_vector_type(4))) unsigned short u16x4;
typedef __attribute__((ext_vector_type(8))) unsigned short u16x8;
typedef unsigned int u32;
typedef unsigned short u16;

__device__ __forceinline__ u16 f2bf(float f) {
  union { float f; u32 u; } v; v.f = f;
  u32 r = (v.u + 0x7fffu + ((v.u >> 16) & 1u)) >> 16;
  return (u16)r;
}
__device__ __forceinline__ float bf2f(u16 h) {
  union { u32 u; float f; } v; v.u = ((u32)h) << 16; return v.f;
}
__device__ __forceinline__ float gelu_exact(float v) {
  return 0.5f * v * (1.0f + erff(v * 0.70710678118654752f));
}
__device__ __forceinline__ float gelu_fast(float v) {
  float u = v * (0.7978845608f + 0.0356774081f * v * v);
  float t = __expf(-2.0f * fabsf(u));
  float th = (1.0f - t) / (1.0f + t);
  th = copysignf(th, u);
  return 0.5f * v * (1.0f + th);
}

__device__ __forceinline__ void gll16(const void* g, void* l) {
  __builtin_amdgcn_global_load_lds(
      (const __attribute__((address_space(1))) u32*)g,
      (__attribute__((address_space(3))) u32*)l, 16, 0, 0);
}

// XCD-grouped work remap (kept from r14: FETCH higher but dur slightly better).
__device__ __forceinline__ void xcd_remap(int& M, int& nt) {
  if (((gridDim.x & 7) == 0) && ((gridDim.y & 7) == 0)) {
    int c = blockIdx.x & 7, q = blockIdx.x >> 3;
    M  = ((blockIdx.y >> 3) << 3) + c;
    nt = (q << 3) + (blockIdx.y & 7);
  } else {
    M = blockIdx.y; nt = blockIdx.x;
  }
}

// -------- fused embed + layer-0 gate --------
__global__ __launch_bounds__(256) void embed_gate_kernel(const int* __restrict__ tok,
    const float* __restrict__ sym, const float* __restrict__ emb,
    const float* __restrict__ gw, const float* __restrict__ gb,
    u16* __restrict__ xh, u16* __restrict__ xl,
    int* __restrict__ topk_idx, float* __restrict__ topk_w)
{
  int t = blockIdx.x;
  int b = t >> 11;
  int tk = tok[t];
  int d = threadIdx.x * 4;
  f32x4 e = *(const f32x4*)(emb + (size_t)tk * DM + d);
  f32x4 s = *(const f32x4*)(sym + (size_t)b * DM + d);
  f32x4 v = e + s;
  u16x4 hv, lv;
#pragma unroll
  for (int j = 0; j < 4; ++j) {
    u16 hb = f2bf(v[j]);
    hv[j] = hb;
    lv[j] = f2bf(v[j] - bf2f(hb));
  }
  *(u16x4*)(xh + (size_t)t * DM + d) = hv;
  *(u16x4*)(xl + (size_t)t * DM + d) = lv;

  double a[8] = {0,0,0,0,0,0,0,0};
#pragma unroll
  for (int q = 0; q < 4; ++q) {
    const f32x4* gr = (const f32x4*)(gw + (size_t)(d + q) * 8);
    f32x4 g0 = gr[0], g1 = gr[1];
    double xv = (double)v[q];
    a[0] += xv*(double)g0.x; a[1] += xv*(double)g0.y;
    a[2] += xv*(double)g0.z; a[3] += xv*(double)g0.w;
    a[4] += xv*(double)g1.x; a[5] += xv*(double)g1.y;
    a[6] += xv*(double)g1.z; a[7] += xv*(double)g1.w;
  }
#pragma unroll
  for (int j = 0; j < 8; ++j) {
#pragma unroll
    for (int sh = 32; sh; sh >>= 1) a[j] += __shfl_xor(a[j], sh);
  }
  __shared__ double red[4][8];
  int wave = threadIdx.x >> 6, lane = threadIdx.x & 63;
  if (lane == 0) {
#pragma unroll
    for (int j = 0; j < 8; ++j) red[wave][j] = a[j];
  }
  __syncthreads();
  if (threadIdx.x == 0) {
    double lg[8];
#pragma unroll
    for (int j = 0; j < 8; ++j)
      lg[j] = red[0][j] + red[1][j] + red[2][j] + red[3][j] + (double)gb[j];
    double m = lg[0];
    for (int j = 1; j < 8; ++j) m = lg[j] > m ? lg[j] : m;
    double p[8], sum = 0.0;
    for (int j = 0; j < 8; ++j) { p[j] = exp(lg[j] - m); sum += p[j]; }
    for (int j = 0; j < 8; ++j) p[j] /= sum;
    int j0 = 0; double b0 = p[0];
    for (int j = 1; j < 8; ++j) if (p[j] > b0) { b0 = p[j]; j0 = j; }
    int j1 = (j0 == 0) ? 1 : 0; double b1v = p[j1];
    for (int j = 0; j < 8; ++j) if (j != j0 && p[j] > b1v) { b1v = p[j]; j1 = j; }
    topk_idx[t*2]   = j0; topk_idx[t*2+1] = j1;
    topk_w[t*2]     = (float)b0; topk_w[t*2+1] = (float)b1v;
  }
}

// meta: [0..7]=totals, [8..16]=offsets, [32..103]=tiletab256, [104..239]=tiletab128,
//       [256..511]=blockcnt[32][8], [512..767]=blockbase[32][8]
__global__ __launch_bounds__(256) void count_kernel(const int* __restrict__ topk_idx,
    int* __restrict__ meta)
{
  __shared__ int hist[8];
  int tid = threadIdx.x;
  if (tid < 8) hist[tid] = 0;
  __syncthreads();
  int t = blockIdx.x * 256 + tid;
  atomicAdd(&hist[topk_idx[t*2] & 7], 1);
  atomicAdd(&hist[topk_idx[t*2+1] & 7], 1);
  __syncthreads();
  if (tid < 8) meta[256 + blockIdx.x * 8 + tid] = hist[tid];
}

__global__ __launch_bounds__(64) void scan_kernel(int* __restrict__ meta)
{
  __shared__ int tot[8], off[9], tb2[8], tb1[8];
  int lane = threadIdx.x;
  if (lane < 8) {
    int s = 0;
    for (int b = 0; b < 32; ++b) s += meta[256 + b * 8 + lane];
    tot[lane] = s;
  }
  __syncthreads();
  if (lane == 0) {
    int s = 0, n2 = 0, n1 = 0;
    for (int e = 0; e < 8; ++e) {
      off[e] = s; s += tot[e];
      tb2[e] = n2; n2 += (tot[e] + 255) >> 8;
      tb1[e] = n1; n1 += (tot[e] + 127) >> 7;
    }
    off[8] = s;
    for (int i = n2; i < MT256; ++i) meta[32 + i] = -1;
    for (int i = n1; i < MT128; ++i) meta[104 + i] = -1;
  }
  __syncthreads();
  if (lane < 9) meta[8 + lane] = off[lane];
  if (lane < 8) {
    meta[lane] = tot[lane];
    int n2 = (tot[lane] + 255) >> 8;
    for (int i = 0; i < n2; ++i) meta[32 + tb2[lane] + i] = (lane << 16) | i;
    int n1 = (tot[lane] + 127) >> 7;
    for (int i = 0; i < n1; ++i) meta[104 + tb1[lane] + i] = (lane << 16) | i;
    int run = off[lane];
    for (int b = 0; b < 32; ++b) {
      meta[512 + b * 8 + lane] = run;
      run += meta[256 + b * 8 + lane];
    }
  }
}

__global__ __launch_bounds__(256) void scatter_kernel(int* __restrict__ topk_idx,
    const int* __restrict__ meta, int* __restrict__ pair_token)
{
  __shared__ int hist[8];
  __shared__ int base[8];
  int tid = threadIdx.x;
  if (tid < 8) { hist[tid] = 0; base[tid] = meta[512 + blockIdx.x * 8 + tid]; }
  __syncthreads();
  int t = blockIdx.x * 256 + tid;
#pragma unroll
  for (int k = 0; k < 2; ++k) {
    int e = topk_idx[t*2 + k] & 7;
    int pos = atomicAdd(&hist[e], 1);
    int slot = base[e] + pos;
    pair_token[slot] = t;
    topk_idx[t*2 + k] = e | (slot << 3);
  }
}

// ------------- weight transpose+split: f32 [K][N] -> bf16 hi/lo [N][K] -------------
template<bool LO>
__global__ __launch_bounds__(256) void transpose_kernel(const float* __restrict__ src,
    u16* __restrict__ dsth, u16* __restrict__ dstl, int K, int N)
{
  __shared__ float tile[64][65];
  int e = blockIdx.z;
  const float* s = src + (size_t)e * K * N;
  size_t dbase = (size_t)e * K * N;
  int n0 = blockIdx.x * 64, k0 = blockIdx.y * 64;
  int tid = threadIdx.x;
#pragma unroll
  for (int j = 0; j < 4; ++j) {
    int kl = j * 16 + (tid >> 4);
    int nn = (tid & 15) * 4;
    f32x4 v = *(const f32x4*)(s + (size_t)(k0 + kl) * N + n0 + nn);
    tile[nn + 0][kl] = v.x;
    tile[nn + 1][kl] = v.y;
    tile[nn + 2][kl] = v.z;
    tile[nn + 3][kl] = v.w;
  }
  __syncthreads();
#pragma unroll
  for (int it = 0; it < 2; ++it) {
    int task = it * 256 + tid;
    int nr = task >> 3;
    int ch = task & 7;
    u16x8 oh, ol;
#pragma unroll
    for (int j = 0; j < 8; ++j) {
      float v = tile[nr][ch*8 + j];
      u16 hb = f2bf(v);
      oh[j] = hb;
      if (LO) ol[j] = f2bf(v - bf2f(hb));
    }
    size_t doff = dbase + (size_t)(n0 + nr) * K + k0 + ch*8;
    *(u16x8*)(dsth + doff) = oh;
    if (LO) *(u16x8*)(dstl + doff) = ol;
  }
}

// ---- W2G[e] = w2[e] @ gw1  ([E][DFF][8], f32) ----
__global__ __launch_bounds__(256) void w2g_kernel(const float* __restrict__ w2,
    const float* __restrict__ gw, float* __restrict__ w2g)
{
  int wid = blockIdx.x * 4 + (threadIdx.x >> 6);
  int lane = threadIdx.x & 63;
  int e = wid >> 12, f = wid & 4095;
  const float* row = w2 + ((size_t)e * DFF + f) * DM;
  float a0=0,a1=0,a2=0,a3=0,a4=0,a5=0,a6=0,a7=0;
  for (int i = 0; i < 4; ++i) {
    int d0 = i * 256 + lane * 4;
    f32x4 xv = *(const f32x4*)(row + d0);
#pragma unroll
    for (int q = 0; q < 4; ++q) {
      const f32x4* gr = (const f32x4*)(gw + (size_t)(d0 + q) * 8);
      f32x4 g0 = gr[0], g1 = gr[1];
      float xq = xv[q];
      a0 += xq*g0.x; a1 += xq*g0.y; a2 += xq*g0.z; a3 += xq*g0.w;
      a4 += xq*g1.x; a5 += xq*g1.y; a6 += xq*g1.z; a7 += xq*g1.w;
    }
  }
  float acc[8] = {a0,a1,a2,a3,a4,a5,a6,a7};
#pragma unroll
  for (int j = 0; j < 8; ++j) {
#pragma unroll
    for (int sh = 32; sh; sh >>= 1) acc[j] += __shfl_xor(acc[j], sh);
  }
  if (lane == 0) {
#pragma unroll
    for (int j = 0; j < 8; ++j) w2g[(size_t)wid * 8 + j] = acc[j];
  }
}

__global__ __launch_bounds__(256) void b2g_kernel(const float* __restrict__ b2,
    const float* __restrict__ gw, float* __restrict__ b2g)
{
  int w = blockIdx.x * 4 + (threadIdx.x >> 6);
  int lane = threadIdx.x & 63;
  int e = w >> 3, j = w & 7;
  float acc = 0.f;
  for (int i = 0; i < 16; ++i) {
    int d = i * 64 + lane;
    acc += b2[(size_t)e * DM + d] * gw[(size_t)d * 8 + j];
  }
#pragma unroll
  for (int sh = 32; sh; sh >>= 1) acc += __shfl_xor(acc, sh);
  if (lane == 0) b2g[w] = acc;
}

// ---- layer-1 gate: sums Rpart partials inline (fixed order, deterministic) ----
__global__ __launch_bounds__(256) void gate1_kernel(const float* __restrict__ Rpart,
    const float* __restrict__ b2g, const float* __restrict__ gb,
    int* __restrict__ topk_idx, float* __restrict__ topk_w)
{
  int t = blockIdx.x * 256 + threadIdx.x;
  int v0 = topk_idx[t*2], v1 = topk_idx[t*2+1];
  int e0 = v0 & 7, e1 = v1 & 7;
  int s0 = v0 >> 3, s1 = v1 >> 3;
  float r0[8] = {0,0,0,0,0,0,0,0}, r1[8] = {0,0,0,0,0,0,0,0};
  for (int nt = 0; nt < 16; ++nt) {
    const float* p0r = Rpart + ((size_t)nt * NPAIR + s0) * 8;
    const float* p1r = Rpart + ((size_t)nt * NPAIR + s1) * 8;
#pragma unroll
    for (int j = 0; j < 8; ++j) { r0[j] += p0r[j]; r1[j] += p1r[j]; }
  }
  double w0 = (double)topk_w[t*2], w1 = (double)topk_w[t*2+1];
  double a[8];
#pragma unroll
  for (int j = 0; j < 8; ++j)
    a[j] = w0 * ((double)r0[j] + (double)b2g[e0*8+j])
         + w1 * ((double)r1[j] + (double)b2g[e1*8+j])
         + (double)gb[j];
  double m = a[0];
  for (int j = 1; j < 8; ++j) m = a[j] > m ? a[j] : m;
  double p[8], sum = 0.0;
  for (int j = 0; j < 8; ++j) { p[j] = exp(a[j] - m); sum += p[j]; }
  for (int j = 0; j < 8; ++j) p[j] /= sum;
  int j0 = 0; double b0 = p[0];
  for (int j = 1; j < 8; ++j) if (p[j] > b0) { b0 = p[j]; j0 = j; }
  int j1 = (j0 == 0) ? 1 : 0; double b1v = p[j1];
  for (int j = 0; j < 8; ++j) if (j != j0 && p[j] > b1v) { b1v = p[j]; j1 = j; }
  topk_idx[t*2]   = j0; topk_idx[t*2+1] = j1;
  topk_w[t*2]     = (float)b0; topk_w[t*2+1] = (float)b1v;
}

// ====== 256x256 grouped GEMM, BK=64, 8-phase, counted vmcnt ======
// Fragment LDS reads: invariant base + compile-time immediates (unroll x2 -> par const).
// outh = bf16(gelu_exact) + fused R-partials via W2G  [L0-GEMM1]
template<int K0, int NSEG, int NTOT, bool GATHER>
__global__ __launch_bounds__(512, 2) void gemm256_kernel(
    const u16* __restrict__ Ah, const u16* __restrict__ Al,
    const u16* __restrict__ Bh, const u16* __restrict__ Bl,
    const float* __restrict__ bias, const int* __restrict__ off,
    const int* __restrict__ tiletab, const int* __restrict__ pair_token,
    u16* __restrict__ outh, const float* __restrict__ W2G,
    float* __restrict__ Rpart)
{
  constexpr int NT = (K0 * NSEG) / 64;
  static_assert(NT >= 2 && (NT & 1) == 0, "");
  int Mi, nti;
  xcd_remap(Mi, nti);
  const int tt = tiletab[Mi];
  if (tt < 0) return;
  const int e  = tt >> 16;
  const int mt = tt & 0xffff;
  const int off_e = off[e], off_e1 = off[e + 1];
  const int p0 = off_e + mt * 256;
  const int n0 = nti * 256;

  __shared__ __align__(16) u16 ALs[2][2][8192];
  __shared__ __align__(16) u16 BLs[2][2][8192];

  const int tid  = threadIdx.x;
  const int lane = tid & 63;
  const int wave = tid >> 6;
  const int wm = wave >> 2;
  const int wn = wave & 3;
  const int wbase = tid & 448;

  size_t aoff[2], boff[2];
#pragma unroll
  for (int i = 0; i < 2; ++i) {
    int c = i * 512 + tid;
    int r = c >> 2;
    int cs = (c & 3) ^ ((r >> 1) & 3);
    int idx = p0 + r;
    if (idx >= off_e1) idx = p0;
    int ar = GATHER ? pair_token[idx] : idx;
    aoff[i] = (size_t)ar * K0 + (size_t)(cs * 8);
    boff[i] = ((size_t)e * NTOT + n0 + r) * K0 + (size_t)(cs * 8);
  }

  auto stageA = [&](int t, int kh) {
    int kk = t * 64 + kh * 32;
    int seg = (NSEG == 3) ? (kk >> 10) : 0;
    int kc  = (NSEG == 3) ? (kk & (K0 - 1)) : kk;
    const u16* base = (NSEG == 3 && seg == 1) ? Al : Ah;
    u16* dst = &ALs[t & 1][kh][0];
#pragma unroll
    for (int i = 0; i < 2; ++i)
      gll16(base + aoff[i] + kc, dst + (i * 512 + wbase) * 8);
  };
  auto stageB = [&](int t, int kh) {
    int kk = t * 64 + kh * 32;
    int seg = (NSEG == 3) ? (kk >> 10) : 0;
    int kc  = (NSEG == 3) ? (kk & (K0 - 1)) : kk;
    const u16* base = (NSEG == 3 && seg == 2) ? Bl : Bh;
    u16* dst = &BLs[t & 1][kh][0];
#pragma unroll
    for (int i = 0; i < 2; ++i)
      gll16(base + boff[i] + kc, dst + (i * 512 + wbase) * 8);
  };

  f32x4 acc[8][4];
  const f32x4 fzero = {0.f, 0.f, 0.f, 0.f};
#pragma unroll
  for (int m = 0; m < 8; ++m)
#pragma unroll
    for (int n = 0; n < 4; ++n) acc[m][n] = fzero;

  // invariant fragment bases: swizzle chunk = (lane>>4) ^ (((lane&15)>>1)&3)
  // (row>>1)&3 reduces to ((lane&15)>>1)&3 for all fragments — frag step = 1024 B.
  const int swzB = (((lane >> 4) ^ (((lane & 15) >> 1) & 3)) << 4);
  const char* Abase = (const char*)&ALs[0][0][0]
      + (wm * 128 + (lane & 15)) * 64 + swzB;
  const char* Bbase = (const char*)&BLs[0][0][0]
      + (wn * 64 + (lane & 15)) * 64 + swzB;

#define RDA4(dst, POFS, MB)                                                     \
  { _Pragma("unroll") for (int mf = 0; mf < 4; ++mf)                            \
      dst[mf] = *(const bf16x8*)(Abase + (POFS) + ((MB) + mf) * 1024); }
#define RDB4(dst, POFS)                                                         \
  { _Pragma("unroll") for (int nf = 0; nf < 4; ++nf)                            \
      dst[nf] = *(const bf16x8*)(Bbase + (POFS) + nf * 1024); }

#define MMBLK(MB, A4, B4)                                                       \
  {                                                                             \
    __builtin_amdgcn_s_setprio(1);                                              \
    _Pragma("unroll")                                                           \
    for (int mf = 0; mf < 4; ++mf)                                              \
      _Pragma("unroll")                                                         \
      for (int nf = 0; nf < 4; ++nf)                                            \
        acc[(MB) + mf][nf] = __builtin_amdgcn_mfma_f32_16x16x32_bf16(           \
            (A4)[mf], (B4)[nf], acc[(MB) + mf][nf], 0, 0, 0);                   \
    __builtin_amdgcn_s_setprio(0);                                              \
  }

#define TILE256(t, POFS)                                                        \
  {                                                                             \
    bf16x8 bA[4], aA[4], aB[4], bC[4], aC[4], aD[4];                            \
    RDB4(bA, (POFS));                                                           \
    RDA4(aA, (POFS), 0);                                                        \
    if ((t) + 1 < NT) stageA((t) + 1, 1);                                       \
    __builtin_amdgcn_s_barrier();                                               \
    MMBLK(0, aA, bA);                                                           \
    __builtin_amdgcn_s_barrier();                                               \
    RDA4(aB, (POFS), 4);                                                        \
    if ((t) + 1 < NT) stageB((t) + 1, 1);                                       \
    __builtin_amdgcn_s_barrier();                                               \
    MMBLK(4, aB, bA);                                                           \
    if ((t) + 1 < NT) { asm volatile("s_waitcnt vmcnt(8)" ::: "memory"); }      \
    else              { asm volatile("s_waitcnt vmcnt(0)" ::: "memory"); }      \
    __builtin_amdgcn_s_barrier();                                               \
    asm volatile("" ::: "memory");                                              \
    RDB4(bC, (POFS) + 16384);                                                   \
    RDA4(aC, (POFS) + 16384, 0);                                                \
    if ((t) + 2 < NT) stageA((t) + 2, 0);                                       \
    __builtin_amdgcn_s_barrier();                                               \
    MMBLK(0, aC, bC);                                                           \
    __builtin_amdgcn_s_barrier();                                               \
    RDA4(aD, (POFS) + 16384, 4);                                                \
    if ((t) + 2 < NT) stageB((t) + 2, 0);                                       \
    __builtin_amdgcn_s_barrier();                                               \
    MMBLK(4, aD, bC);                                                           \
    if ((t) + 1 < NT) {                                                         \
      if ((t) + 2 < NT) { asm volatile("s_waitcnt vmcnt(8)" ::: "memory"); }    \
      else              { asm volatile("s_waitcnt vmcnt(4)" ::: "memory"); }    \
      __builtin_amdgcn_s_barrier();                                             \
      asm volatile("" ::: "memory");                                            \
    }                                                                           \
  }

  stageA(0, 0); stageB(0, 0);
  stageA(0, 1); stageB(0, 1);
  stageA(1, 0); stageB(1, 0);
  asm volatile("s_waitcnt vmcnt(8)" ::: "memory");
  __builtin_amdgcn_s_barrier();
  asm volatile("" ::: "memory");

  for (int t = 0; t < NT; t += 2) {
    TILE256(t, 0);           // par = 0
    TILE256(t + 1, 32768);   // par = 1
  }
#undef TILE256
#undef MMBLK
#undef RDA4
#undef RDB4

  float bv[4];
#pragma unroll
  for (int nf = 0; nf < 4; ++nf)
    bv[nf] = bias[(size_t)e * NTOT + n0 + wn * 64 + nf * 16 + (lane & 15)];

  __syncthreads();                       // reclaim LDS for Rpt
  float* Rpt = (float*)&ALs[0][0][0];    // [4 wn][256 rows][8] f32 = 32 KB
  f32x4 wg0[4], wg1[4];
#pragma unroll
  for (int nf = 0; nf < 4; ++nf) {
    int col = n0 + wn * 64 + nf * 16 + (lane & 15);
    const float* wp = W2G + ((size_t)e * NTOT + col) * 8;
    wg0[nf] = *(const f32x4*)wp;
    wg1[nf] = *(const f32x4*)(wp + 4);
  }
#pragma unroll
  for (int mf = 0; mf < 8; ++mf) {
    f32x4 pr0[4], pr1[4];
#pragma unroll
    for (int r = 0; r < 4; ++r) { pr0[r] = fzero; pr1[r] = fzero; }
    int rbase = p0 + wm * 128 + mf * 16 + ((lane >> 4) << 2);
#pragma unroll
    for (int nf = 0; nf < 4; ++nf) {
      int col = n0 + wn * 64 + nf * 16 + (lane & 15);
#pragma unroll
      for (int r = 0; r < 4; ++r) {
        float v = gelu_exact(acc[mf][nf][r] + bv[nf]);
        if (rbase + r < off_e1)
          outh[(size_t)(rbase + r) * NTOT + col] = f2bf(v);
        pr0[r] += v * wg0[nf];
        pr1[r] += v * wg1[nf];
      }
    }
#pragma unroll
    for (int r = 0; r < 4; ++r) {
#pragma unroll
      for (int sh = 1; sh < 16; sh <<= 1) {
#pragma unroll
        for (int q = 0; q < 4; ++q) {
          pr0[r][q] += __shfl_xor(pr0[r][q], sh);
          pr1[r][q] += __shfl_xor(pr1[r][q], sh);
        }
      }
      if ((lane & 15) == 0) {
        int rl = wm * 128 + mf * 16 + ((lane >> 4) << 2) + r;
        float* dst = Rpt + ((size_t)(wn * 256 + rl)) * 8;
        *(f32x4*)dst = pr0[r];
        *(f32x4*)(dst + 4) = pr1[r];
      }
    }
  }
  __syncthreads();
  for (int i = tid; i < 256 * 8; i += 512) {
    int rl = i >> 3, j = i & 7;
    float ssum = Rpt[(size_t)(0 * 256 + rl) * 8 + j]
               + Rpt[(size_t)(1 * 256 + rl) * 8 + j]
               + Rpt[(size_t)(2 * 256 + rl) * 8 + j]
               + Rpt[(size_t)(3 * 256 + rl) * 8 + j];
    int p = p0 + rl;
    if (p < off_e1)
      Rpart[((size_t)nti * NPAIR + p) * 8 + j] = ssum;
  }
}

// ====== 128x128 grouped GEMM, BK=32, ring-2, 32KB LDS ======
// Fragment reads: invariant base + imm offsets (unroll x2 -> buf const).
// MODE 0: outh = bf16(gelu_fast)   [L1-GEMM1]
// MODE 2: outy = bf16(acc + bias)  [GEMM2s -> yb]
template<int K0, int NTOT, bool GATHER, int MODE>
__global__ __launch_bounds__(256, 4) void gemm128_kernel(
    const u16* __restrict__ Ah, const u16* __restrict__ Bh,
    const float* __restrict__ bias, const int* __restrict__ off,
    const int* __restrict__ tiletab, const int* __restrict__ pair_token,
    u16* __restrict__ outp)
{
  constexpr int NT = K0 / 32;
  static_assert((NT & 1) == 0, "");
  int Mi, nti;
  xcd_remap(Mi, nti);
  const int tt = tiletab[Mi];
  if (tt < 0) return;
  const int e  = tt >> 16;
  const int mt = tt & 0xffff;
  const int off_e = off[e], off_e1 = off[e + 1];
  const int p0 = off_e + mt * 128;
  const int n0 = nti * 128;

  __shared__ __align__(16) u16 AL[2][4096];
  __shared__ __align__(16) u16 BL[2][4096];

  const int tid  = threadIdx.x;
  const int lane = tid & 63;
  const int wave = tid >> 6;
  const int wm = wave >> 1, wn = wave & 1;
  const int wbase = tid & 192;

  size_t aoff[2], boff[2];
#pragma unroll
  for (int i = 0; i < 2; ++i) {
    int c = i * 256 + tid;
    int r = c >> 2;
    int cs = (c & 3) ^ ((r >> 1) & 3);
    int idx = p0 + r;
    if (idx >= off_e1) idx = p0;
    int ar = GATHER ? pair_token[idx] : idx;
    aoff[i] = (size_t)ar * K0 + (size_t)(cs * 8);
    boff[i] = ((size_t)e * NTOT + n0 + r) * K0 + (size_t)(cs * 8);
  }

  auto stage = [&](int b, int t) {
    int kc = t * 32;
#pragma unroll
    for (int i = 0; i < 2; ++i) {
      int cb = i * 256 + wbase;
      gll16(Ah + aoff[i] + kc, &AL[b][cb * 8]);
      gll16(Bh + boff[i] + kc, &BL[b][cb * 8]);
    }
  };

  f32x4 acc[4][4];
  const f32x4 fzero = {0.f, 0.f, 0.f, 0.f};
#pragma unroll
  for (int m = 0; m < 4; ++m)
#pragma unroll
    for (int n = 0; n < 4; ++n) acc[m][n] = fzero;

  const int swzB = (((lane >> 4) ^ (((lane & 15) >> 1) & 3)) << 4);
  const char* Abase = (const char*)&AL[0][0]
      + (wm * 64 + (lane & 15)) * 64 + swzB;
  const char* Bbase = (const char*)&BL[0][0]
      + (wn * 64 + (lane & 15)) * 64 + swzB;

#define MMA128(BOFS)                                                            \
  {                                                                             \
    bf16x8 af[4], bf[4];                                                        \
    _Pragma("unroll")                                                           \
    for (int m = 0; m < 4; ++m)                                                 \
      af[m] = *(const bf16x8*)(Abase + (BOFS) + m * 1024);                      \
    _Pragma("unroll")                                                           \
    for (int n = 0; n < 4; ++n)                                                 \
      bf[n] = *(const bf16x8*)(Bbase + (BOFS) + n * 1024);                      \
    __builtin_amdgcn_s_setprio(1);                                              \
    _Pragma("unroll")                                                           \
    for (int m = 0; m < 4; ++m)                                                 \
      _Pragma("unroll")                                                         \
      for (int n = 0; n < 4; ++n)                                               \
        acc[m][n] = __builtin_amdgcn_mfma_f32_16x16x32_bf16(                    \
            af[m], bf[n], acc[m][n], 0, 0, 0);                                  \
    __builtin_amdgcn_s_setprio(0);                                              \
  }

  stage(0, 0);
  __syncthreads();

  for (int t = 0; t < NT; t += 2) {
    stage(1, t + 1);                 // t+1 < NT always (NT even, t <= NT-2)
    MMA128(0);
    __syncthreads();
    if (t + 2 < NT) stage(0, t + 2);
    MMA128(8192);
    __syncthreads();
  }
#undef MMA128

  float bv[4];
#pragma unroll
  for (int n = 0; n < 4; ++n)
    bv[n] = bias[(size_t)e * NTOT + n0 + wn * 64 + n * 16 + (lane & 15)];

#pragma unroll
  for (int m = 0; m < 4; ++m) {
    int rbase = p0 + wm * 64 + m * 16 + ((lane >> 4) << 2);
#pragma unroll
    for (int n = 0; n < 4; ++n) {
      int col = n0 + wn * 64 + n * 16 + (lane & 15);
#pragma unroll
      for (int r = 0; r < 4; ++r) {
        int rowp = rbase + r;
        if (rowp < off_e1) {
          float v = acc[m][n][r] + bv[n];
          if constexpr (MODE == 0) v = gelu_fast(v);
          outp[(size_t)rowp * NTOT + col] = f2bf(v);
        }
      }
    }
  }
}

// ---------------- combine (layer 0): xh = bf16(w0*yb[s0] + w1*yb[s1]) ----------------
__global__ __launch_bounds__(256) void combine0_kernel(const u16* __restrict__ yb,
    const int* __restrict__ topk_idx, const float* __restrict__ topk_w,
    u16* __restrict__ xh)
{
  int t = blockIdx.x;
  int d = threadIdx.x * 4;
  int s0 = topk_idx[t*2] >> 3, s1 = topk_idx[t*2 + 1] >> 3;
  float w0 = topk_w[t*2], w1 = topk_w[t*2 + 1];
  u16x4 y0 = *(const u16x4*)(yb + (size_t)s0 * DM + d);
  u16x4 y1 = *(const u16x4*)(yb + (size_t)s1 * DM + d);
  u16x4 hv;
#pragma unroll
  for (int j = 0; j < 4; ++j)
    hv[j] = f2bf(bf2f(y0[j]) * w0 + bf2f(y1[j]) * w1);
  *(u16x4*)(xh + (size_t)t * DM + d) = hv;
}

// ---------------- combine (layer 1) + LayerNorm ----------------
__global__ __launch_bounds__(256) void combine1_ln_kernel(const u16* __restrict__ yb,
    const int* __restrict__ topk_idx, const float* __restrict__ topk_w,
    const float* __restrict__ g, const float* __restrict__ b, float* __restrict__ out)
{
  int t = blockIdx.x;
  int d = threadIdx.x * 4;
  int s0 = topk_idx[t*2] >> 3, s1 = topk_idx[t*2 + 1] >> 3;
  float w0 = topk_w[t*2], w1 = topk_w[t*2 + 1];
  u16x4 y0 = *(const u16x4*)(yb + (size_t)s0 * DM + d);
  u16x4 y1 = *(const u16x4*)(yb + (size_t)s1 * DM + d);
  f32x4 v;
#pragma unroll
  for (int j = 0; j < 4; ++j)
    v[j] = bf2f(y0[j]) * w0 + bf2f(y1[j]) * w1;
  float s = v.x + v.y + v.z + v.w;
  float sq = v.x*v.x + v.y*v.y + v.z*v.z + v.w*v.w;
#pragma unroll
  for (int sh = 32; sh; sh >>= 1) { s += __shfl_xor(s, sh); sq += __shfl_xor(sq, sh); }
  __shared__ float red[8];
  int wave = threadIdx.x >> 6, lane = threadIdx.x & 63;
  if (lane == 0) { red[wave] = s; red[4 + wave] = sq; }
  __syncthreads();
  s = red[0] + red[1] + red[2] + red[3];
  sq = red[4] + red[5] + red[6] + red[7];
  float mu = s * (1.0f / DM);
  float var = sq * (1.0f / DM) - mu * mu;
  float inv = rsqrtf(var + LN_EPS);
  f32x4 gv = *(const f32x4*)(g + d);
  f32x4 bv = *(const f32x4*)(b + d);
  f32x4 o;
  o.x = (v.x - mu) * inv * gv.x + bv.x;
  o.y = (v.y - mu) * inv * gv.y + bv.y;
  o.z = (v.z - mu) * inv * gv.z + bv.z;
  o.w = (v.w - mu) * inv * gv.w + bv.w;
  *(f32x4*)(out + (size_t)t * DM + d) = o;
}

extern "C" void kernel_launch(void* const* d_in, const int* in_sizes, int n_in,
                              void* d_out, int out_size, void* d_ws, size_t ws_size,
                              hipStream_t stream)
{
  const int*   tokens = (const int*)d_in[0];
  const float* sym    = (const float*)d_in[1];
  const float* emb    = (const float*)d_in[2];
  const float* gate_w = (const float*)d_in[3];
  const float* gate_b = (const float*)d_in[4];
  const float* w1     = (const float*)d_in[5];
  const float* b1     = (const float*)d_in[6];
  const float* w2     = (const float*)d_in[7];
  const float* b2     = (const float*)d_in[8];
  const float* ln_g   = (const float*)d_in[9];
  const float* ln_b   = (const float*)d_in[10];

  char* ws = (char*)d_ws;
  u16*   yb  = (u16*)  (ws);                     //  33.5MB [16384][1024] bf16 y
  u16*   xh  = (u16*)  (ws + 33554432);          //  16MB
  u16*   xl  = (u16*)  (ws + 50331648);          //  16MB
  u16*   hh  = (u16*)  (ws + 67108864);          // 128MB [16384][4096] bf16
  float* W2G   = (float*)(ws + 201326592);       //   1MB [8][4096][8]
  float* Rpart = (float*)(ws + 202375168);       //  16MB [16][16384][8]
  float* B2G   = (float*)(ws + 219152384);       //  256B
  u16*   wTh = (u16*)  (ws + 335544320);         //  64MB
  u16*   wTl = (u16*)  (ws + 402653184);         //  64MB (L0-GEMM1 only)
  int*   pair_token = (int*)  (ws + 469762048);  //  64KB
  int*   topk_idx   = (int*)  (ws + 469893120);  //  64KB (expert | slot<<3)
  float* topk_w     = (float*)(ws + 469958656);  //  64KB
  int*   meta       = (int*)  (ws + 470024192);  //  3KB

  // ================= layer 0 =================
  embed_gate_kernel<<<T_TOK, 256, 0, stream>>>(tokens, sym, emb, gate_w, gate_b,
                                               xh, xl, topk_idx, topk_w);
  count_kernel<<<T_TOK / 256, 256, 0, stream>>>(topk_idx, meta);
  scan_kernel<<<1, 64, 0, stream>>>(meta);
  scatter_kernel<<<T_TOK / 256, 256, 0, stream>>>(topk_idx, meta, pair_token);

  w2g_kernel<<<NE * DFF / 4, 256, 0, stream>>>(w2, gate_w + (size_t)DM * NE, W2G);
  b2g_kernel<<<16, 256, 0, stream>>>(b2, gate_w + (size_t)DM * NE, B2G);

  transpose_kernel<true><<<dim3(DFF / 64, DM / 64, NE), 256, 0, stream>>>(
      w1, wTh, wTl, DM, DFF);
  gemm256_kernel<DM, 3, DFF, true><<<dim3(DFF / 256, MT256), 512, 0, stream>>>(
      xh, xl, wTh, wTl, b1, meta + 8, meta + 32, pair_token, hh, W2G, Rpart);

  transpose_kernel<false><<<dim3(DM / 64, DFF / 64, NE), 256, 0, stream>>>(
      w2, wTh, nullptr, DFF, DM);
  gemm128_kernel<DFF, DM, false, 2><<<dim3(DM / 128, MT128), 256, 0, stream>>>(
      hh, wTh, b2, meta + 8, meta + 104, pair_token, yb);

  combine0_kernel<<<T_TOK, 256, 0, stream>>>(yb, topk_idx, topk_w, xh);

  // ================= layer 1 =================
  gate1_kernel<<<T_TOK / 256, 256, 0, stream>>>(Rpart, B2G, gate_b + NE,
                                                topk_idx, topk_w);
  count_kernel<<<T_TOK / 256, 256, 0, stream>>>(topk_idx, meta);
  scan_kernel<<<1, 64, 0, stream>>>(meta);
  scatter_kernel<<<T_TOK / 256, 256, 0, stream>>>(topk_idx, meta, pair_token);

  transpose_kernel<false><<<dim3(DFF / 64, DM / 64, NE), 256, 0, stream>>>(
      w1 + (size_t)NE * DM * DFF, wTh, nullptr, DM, DFF);
  gemm128_kernel<DM, DFF, true, 0><<<dim3(DFF / 128, MT128), 256, 0, stream>>>(
      xh, wTh, b1 + (size_t)NE * DFF, meta + 8, meta + 104, pair_token, hh);

  transpose_kernel<false><<<dim3(DM / 64, DFF / 64, NE), 256, 0, stream>>>(
      w2 + (size_t)NE * DFF * DM, wTh, nullptr, DFF, DM);
  gemm128_kernel<DFF, DM, false, 2><<<dim3(DM / 128, MT128), 256, 0, stream>>>(
      hh, wTh, b2 + (size_t)NE * DM, meta + 8, meta + 104, pair_token, yb);

  combine1_ln_kernel<<<T_TOK, 256, 0, stream>>>(yb, topk_idx, topk_w,
                                                ln_g, ln_b, (float*)d_out);
}